// Round 6
// baseline (597.838 us; speedup 1.0000x reference)
//
#include <hip/hip_runtime.h>
#include <cstdint>

typedef unsigned short u16;
typedef unsigned int u32;
typedef __attribute__((ext_vector_type(8))) short s8v;   // 8 bf16 (4 VGPRs)
typedef __attribute__((ext_vector_type(4))) float f4v;   // MFMA acc

#define FCH 256

__device__ __forceinline__ float bf2f(u16 u){ return __uint_as_float(((u32)u)<<16); }
__device__ __forceinline__ u16 f2bf(float x){
  u32 u = __float_as_uint(x);
  u += 0x7fffu + ((u>>16)&1u);
  return (u16)(u>>16);
}
__device__ __forceinline__ uint4 pack8(float4 a, float4 b){
  uint4 o;
  o.x = (u32)f2bf(a.x) | ((u32)f2bf(a.y)<<16);
  o.y = (u32)f2bf(a.z) | ((u32)f2bf(a.w)<<16);
  o.z = (u32)f2bf(b.x) | ((u32)f2bf(b.y)<<16);
  o.w = (u32)f2bf(b.z) | ((u32)f2bf(b.w)<<16);
  return o;
}
__device__ __forceinline__ float seluf(float x){
  const float sc = 1.0507009873554805f, al = 1.6732632423543772f;
  return x > 0.f ? sc*x : sc*al*(__expf(x)-1.f);
}
// Masked 16B load: AND each dword with m (m=0 zeroes the fragment).
__device__ __forceinline__ s8v ldmask(const u16* p, u32 m){
  uint4 r = *reinterpret_cast<const uint4*>(p);
  r.x &= m; r.y &= m; r.z &= m; r.w &= m;
  s8v v; *reinterpret_cast<uint4*>(&v) = r;
  return v;
}
// XCD-stripe swizzle.
__device__ __forceinline__ int xcd_tile(int bid, int nT8){
  return nT8 ? ((bid & 7) * nT8 + (bid >> 3)) : bid;
}

// ---------------------------------------------------------------------------
// Weight packing (fp32 -> bf16 fragments): lane l slot j of frag (kc,nt) =
// B[kc*32 + (l>>4)*8 + j][nt*16 + (l&15)]  (16B/lane contiguous)
// ---------------------------------------------------------------------------
__global__ __launch_bounds__(256) void pack_kernel(
    const float* __restrict__ Wc, const float* __restrict__ Wf, const float* __restrict__ Wg,
    const float* __restrict__ Wr, const float* __restrict__ Ws,
    const float* __restrict__ Wd1, const float* __restrict__ Wd2,
    u16* __restrict__ Bp1, u16* __restrict__ Bp2, u16* __restrict__ Bp0,
    u16* __restrict__ BpD1, u16* __restrict__ BpD2)
{
  int gid = blockIdx.x*256 + threadIdx.x;
  int frag = gid >> 6;
  int lane = gid & 63;
  int q = lane >> 4, i15 = lane & 15;
  u16 v[8];
  u16* dst;
  if (frag < 4096) {                       // Bp1: [Wf|Wg] K=512 (tap-major)
    int layer = frag >> 9, rem = frag & 511;
    int kc = rem >> 5, nt = rem & 31;
    int n = nt*16 + i15;
    const float* W = (n < 256) ? Wf : Wg;
    int nn = (n < 256) ? n : n - 256;
    #pragma unroll
    for (int j = 0; j < 8; ++j) {
      int k = kc*32 + q*8 + j;
      int tap = k >> 8, cin = k & 255;
      v[j] = f2bf(W[((size_t)((layer*2 + tap)*256 + cin))*256 + nn]);
    }
    dst = Bp1 + (size_t)frag*512 + lane*8;
  } else if (frag < 6144) {                // Bp2: [Wr|Ws] K=256
    int f = frag - 4096;
    int layer = f >> 8, rem = f & 255;
    int kc = rem >> 5, nt = rem & 31;
    int n = nt*16 + i15;
    const float* W = (n < 256) ? Wr : Ws;
    int nn = (n < 256) ? n : n - 256;
    #pragma unroll
    for (int j = 0; j < 8; ++j) {
      int k = kc*32 + q*8 + j;
      v[j] = f2bf(W[((size_t)(layer*256 + k))*256 + nn]);
    }
    dst = Bp2 + (size_t)f*512 + lane*8;
  } else if (frag < 6208) {                // Bp0: Wc K=128
    int f = frag - 6144;
    int kc = f >> 4, nt = f & 15;
    int n = nt*16 + i15;
    #pragma unroll
    for (int j = 0; j < 8; ++j) {
      int k = kc*32 + q*8 + j;
      int tap = k >> 6, cin = k & 63;
      v[j] = f2bf(Wc[(size_t)(tap*64 + cin)*256 + n]);
    }
    dst = Bp0 + (size_t)f*512 + lane*8;
  } else if (frag < 6240) {                // BpD1: Wd1 [256,64]
    int f = frag - 6208;
    int kc = f >> 2, nt = f & 3;
    int n = nt*16 + i15;
    #pragma unroll
    for (int j = 0; j < 8; ++j) {
      int k = kc*32 + q*8 + j;
      v[j] = f2bf(Wd1[(size_t)k*64 + n]);
    }
    dst = BpD1 + (size_t)f*512 + lane*8;
  } else if (frag < 6248) {                // BpD2: Wd2 [64,64]
    int f = frag - 6240;
    int kc = f >> 2, nt = f & 3;
    int n = nt*16 + i15;
    #pragma unroll
    for (int j = 0; j < 8; ++j) {
      int k = kc*32 + q*8 + j;
      v[j] = f2bf(Wd2[(size_t)k*64 + n]);
    }
    dst = BpD2 + (size_t)f*512 + lane*8;
  } else return;
  uint4 o;
  o.x = (u32)v[0] | ((u32)v[1] << 16);
  o.y = (u32)v[2] | ((u32)v[3] << 16);
  o.z = (u32)v[4] | ((u32)v[5] << 16);
  o.w = (u32)v[6] | ((u32)v[7] << 16);
  *reinterpret_cast<uint4*>(dst) = o;
}

// ---------------------------------------------------------------------------
// Initial causal conv (dilation 1, no bias): out0 = [x[t-1]|x[t]] @ cat(Wc)
// ---------------------------------------------------------------------------
__global__ __launch_bounds__(256, 2) void conv0_kernel(
    const float* __restrict__ x, u16* __restrict__ outBf,
    const u16* __restrict__ Bp0, int nT8)
{
  __shared__ __align__(16) u16 ldsA[2][2048];
  const int tid = threadIdx.x;
  const int w = tid >> 6, lane = tid & 63, q = lane >> 4, i15 = lane & 15;
  const int rb = xcd_tile(blockIdx.x, nT8) * 64;
  const int sm = tid >> 2, sg = tid & 3;
  const int grow = rb + sm;
  const int tpos = grow & 4095;
  const int sunit = ((sm >> 4)*64 + sg*16 + ((sm & 15) ^ (sg << 1))) * 8;
  const int runit = (q*16 + (i15 ^ (q << 1))) * 8;

  f4v acc[4][4];
  #pragma unroll
  for (int jj = 0; jj < 4; ++jj)
    #pragma unroll
    for (int mt = 0; mt < 4; ++mt)
      acc[jj][mt] = (f4v){0.f,0.f,0.f,0.f};

  float4 f0 = {0.f,0.f,0.f,0.f}, f1 = {0.f,0.f,0.f,0.f};
  if (tpos >= 1) {
    const float* px = x + (size_t)(grow-1)*64 + sg*8;
    f0 = *reinterpret_cast<const float4*>(px);
    f1 = *reinterpret_cast<const float4*>(px + 4);
  }
  *reinterpret_cast<uint4*>(&ldsA[0][sunit]) = pack8(f0, f1);
  s8v bcur[4], bnxt[4];
  #pragma unroll
  for (int jj = 0; jj < 4; ++jj)
    bcur[jj] = *reinterpret_cast<const s8v*>(Bp0 + ((size_t)(w + 4*jj)*64 + lane)*8);
  __syncthreads();

  for (int kc = 0; kc < 4; ++kc) {
    const int cur = kc & 1;
    uint4 an = {0u,0u,0u,0u};
    if (kc < 3) {
      int kg = (kc+1)*32 + sg*8;
      int tap = kg >> 6, col = kg & 63;
      float4 g0 = {0.f,0.f,0.f,0.f}, g1 = {0.f,0.f,0.f,0.f};
      if (tap) {
        const float* px = x + (size_t)grow*64 + col;
        g0 = *reinterpret_cast<const float4*>(px);
        g1 = *reinterpret_cast<const float4*>(px + 4);
      } else if (tpos >= 1) {
        const float* px = x + (size_t)(grow-1)*64 + col;
        g0 = *reinterpret_cast<const float4*>(px);
        g1 = *reinterpret_cast<const float4*>(px + 4);
      }
      an = pack8(g0, g1);
      #pragma unroll
      for (int jj = 0; jj < 4; ++jj)
        bnxt[jj] = *reinterpret_cast<const s8v*>(Bp0 + (((size_t)(kc+1)*16 + (w + 4*jj))*64 + lane)*8);
    }
    s8v af[4];
    #pragma unroll
    for (int mt = 0; mt < 4; ++mt)
      af[mt] = *reinterpret_cast<const s8v*>(&ldsA[cur][mt*512 + runit]);
    #pragma unroll
    for (int jj = 0; jj < 4; ++jj)
      #pragma unroll
      for (int mt = 0; mt < 4; ++mt)
        acc[jj][mt] = __builtin_amdgcn_mfma_f32_16x16x32_bf16(af[mt], bcur[jj], acc[jj][mt], 0,0,0);
    if (kc < 3) {
      *reinterpret_cast<uint4*>(&ldsA[cur ^ 1][sunit]) = an;
      #pragma unroll
      for (int jj = 0; jj < 4; ++jj) bcur[jj] = bnxt[jj];
    }
    __syncthreads();
  }

  #pragma unroll
  for (int jj = 0; jj < 4; ++jj) {
    const int cc = (w + 4*jj)*16 + i15;
    #pragma unroll
    for (int mt = 0; mt < 4; ++mt)
      #pragma unroll
      for (int r = 0; r < 4; ++r) {
        const int g2 = rb + mt*16 + q*4 + r;
        outBf[(size_t)g2*FCH + cc] = f2bf(acc[jj][mt][r]);
      }
  }
}

// ---------------------------------------------------------------------------
// One WaveNet residual layer. M=32, 256 thr, 1024 blocks. Register-diet
// half-chunk pipeline: bb[2][4] (4 B-frags per step, 8 MFMA) instead of
// bb[2][8] -> ~116 total regs -> 4 waves/SIMD (4 blocks/CU resident).
// Latency-hiding capacity = waves x depth: 3x1 (R5) -> 4x1.
// ---------------------------------------------------------------------------
__global__ __launch_bounds__(256, 4) void layer_kernel(
    const u16* __restrict__ inBf, u16* __restrict__ outBf,
    u16* __restrict__ skipB,
    const u16* __restrict__ Bp1, const u16* __restrict__ Bp2,
    const float* __restrict__ br, const float* __restrict__ bs,
    int dil, int first, int nT8)
{
  __shared__ __align__(16) u16 ldsZ[32*264];     // 16.9 KB
  const int tid = threadIdx.x;
  const int w = tid >> 6, lane = tid & 63, q = lane >> 4, i15 = lane & 15;
  const int rb = xcd_tile(blockIdx.x, nT8) * 32;

  f4v acc[8][2];   // [jj: nt=w+4*jj][mt]
  #pragma unroll
  for (int jj = 0; jj < 8; ++jj)
    #pragma unroll
    for (int mt = 0; mt < 2; ++mt)
      acc[jj][mt] = (f4v){0.f,0.f,0.f,0.f};

  // ---------------- stage 1: half-chunk pipelined, A direct from global -----
  {
    u32 a0o[2], a1o[2], am[2];   // u32 element offsets (saddr+voffset form)
    #pragma unroll
    for (int mt = 0; mt < 2; ++mt) {
      const int row = rb + mt*16 + i15;
      const bool v = (row & 4095) >= dil;
      a0o[mt] = (u32)(v ? row - dil : row)*FCH + q*8;
      a1o[mt] = (u32)row*FCH + q*8;
      am[mt]  = v ? 0xffffffffu : 0u;
    }

    s8v bb[2][4], aa[2][2];
    #pragma unroll
    for (int j2 = 0; j2 < 4; ++j2)
      bb[0][j2] = *reinterpret_cast<const s8v*>(Bp1 + ((size_t)(w + 4*j2)*64 + lane)*8);
    #pragma unroll
    for (int mt = 0; mt < 2; ++mt)
      aa[0][mt] = ldmask(inBf + a0o[mt], am[mt]);

    #pragma unroll
    for (int s = 0; s < 32; ++s) {
      const int kc = s >> 1, h = s & 1;
      if (s + 1 < 32) {
        const int sn = s + 1, kcn = sn >> 1, hn = sn & 1;
        #pragma unroll
        for (int j2 = 0; j2 < 4; ++j2)
          bb[sn & 1][j2] = *reinterpret_cast<const s8v*>(
              Bp1 + (((size_t)kcn*32 + (w + 16*hn + 4*j2))*64 + lane)*8);
        if (hn == 0) {   // next step begins chunk kcn: prefetch its A frags
          if (kcn < 8) {
            #pragma unroll
            for (int mt = 0; mt < 2; ++mt)
              aa[kcn & 1][mt] = ldmask(inBf + a0o[mt] + kcn*32, am[mt]);
          } else {
            #pragma unroll
            for (int mt = 0; mt < 2; ++mt)
              aa[kcn & 1][mt] = *reinterpret_cast<const s8v*>(inBf + a1o[mt] + (kcn - 8)*32);
          }
        }
      }
      __builtin_amdgcn_s_setprio(1);
      #pragma unroll
      for (int j2 = 0; j2 < 4; ++j2)
        #pragma unroll
        for (int mt = 0; mt < 2; ++mt)
          acc[h*4 + j2][mt] = __builtin_amdgcn_mfma_f32_16x16x32_bf16(
              aa[kc & 1][mt], bb[s & 1][j2], acc[h*4 + j2][mt], 0,0,0);
      __builtin_amdgcn_s_setprio(0);
    }
  }

  // -------- issue stage-2 step0 B loads now (latency hides under exp) -------
  s8v s2b[2][4];
  #pragma unroll
  for (int j2 = 0; j2 < 4; ++j2)
    s2b[0][j2] = *reinterpret_cast<const s8v*>(Bp2 + ((size_t)(w + 4*j2)*64 + lane)*8);

  // ---------------- activation: Z -> LDS (C-layout -> row-major) ------------
  #pragma unroll
  for (int jj = 0; jj < 4; ++jj) {
    const int colb = (w + 4*jj)*16 + i15;
    #pragma unroll
    for (int mt = 0; mt < 2; ++mt)
      #pragma unroll
      for (int r = 0; r < 4; ++r) {
        float f = acc[jj][mt][r];
        float g = acc[jj+4][mt][r];
        float z = (1.f - 2.f/(__expf(2.f*f) + 1.f)) * (1.f/(1.f + __expf(-g)));
        ldsZ[(mt*16 + q*4 + r)*264 + colb] = f2bf(z);
      }
  }
  // zero acc for stage 2 (residual/skip/bias added in epilogue, f32)
  #pragma unroll
  for (int jj = 0; jj < 8; ++jj)
    #pragma unroll
    for (int mt = 0; mt < 2; ++mt)
      acc[jj][mt] = (f4v){0.f,0.f,0.f,0.f};
  __syncthreads();   // the ONLY barrier in this kernel

  // ---------------- stage 2 (half-chunk pipelined from ldsZ + global B) -----
  {
    s8v zf[2][2];
    #pragma unroll
    for (int mt = 0; mt < 2; ++mt)
      zf[0][mt] = *reinterpret_cast<const s8v*>(&ldsZ[(mt*16 + i15)*264 + q*8]);
    #pragma unroll
    for (int s = 0; s < 16; ++s) {
      const int kc = s >> 1, h = s & 1;
      if (s + 1 < 16) {
        const int sn = s + 1, kcn = sn >> 1, hn = sn & 1;
        #pragma unroll
        for (int j2 = 0; j2 < 4; ++j2)
          s2b[sn & 1][j2] = *reinterpret_cast<const s8v*>(
              Bp2 + (((size_t)kcn*32 + (w + 16*hn + 4*j2))*64 + lane)*8);
        if (hn == 0) {
          #pragma unroll
          for (int mt = 0; mt < 2; ++mt)
            zf[kcn & 1][mt] = *reinterpret_cast<const s8v*>(&ldsZ[(mt*16 + i15)*264 + kcn*32 + q*8]);
        }
      }
      __builtin_amdgcn_s_setprio(1);
      #pragma unroll
      for (int j2 = 0; j2 < 4; ++j2)
        #pragma unroll
        for (int mt = 0; mt < 2; ++mt)
          acc[h*4 + j2][mt] = __builtin_amdgcn_mfma_f32_16x16x32_bf16(
              zf[kc & 1][mt], s2b[s & 1][j2], acc[h*4 + j2][mt], 0,0,0);
      __builtin_amdgcn_s_setprio(0);
    }
  }

  // ---------------- epilogue: load residual/skip, add bias in f32, store ----
  u16 resv[4][2][4], skv[4][2][4];
  #pragma unroll
  for (int jj = 0; jj < 4; ++jj) {
    const int cc = (w + 4*jj)*16 + i15;
    #pragma unroll
    for (int mt = 0; mt < 2; ++mt)
      #pragma unroll
      for (int r = 0; r < 4; ++r)
        resv[jj][mt][r] = inBf[(size_t)(rb + mt*16 + q*4 + r)*FCH + cc];
  }
  if (!first) {
    #pragma unroll
    for (int jj = 0; jj < 4; ++jj) {
      const int cc = (w + 4*jj)*16 + i15;
      #pragma unroll
      for (int mt = 0; mt < 2; ++mt)
        #pragma unroll
        for (int r = 0; r < 4; ++r)
          skv[jj][mt][r] = skipB[(size_t)(rb + mt*16 + q*4 + r)*FCH + cc];
    }
  }
  #pragma unroll
  for (int jj = 0; jj < 8; ++jj) {
    const int nt = w + 4*jj;
    const bool isR = (jj < 4);
    const int cc = (isR ? nt*16 : (nt-16)*16) + i15;
    const float bias = isR ? br[cc] : bs[cc];
    #pragma unroll
    for (int mt = 0; mt < 2; ++mt)
      #pragma unroll
      for (int r = 0; r < 4; ++r) {
        const int g2 = rb + mt*16 + q*4 + r;
        float vv = acc[jj][mt][r] + bias;
        if (isR) vv += bf2f(resv[jj][mt][r]);
        else if (!first) vv += bf2f(skv[jj-4][mt][r]);
        u16 hv = f2bf(vv);
        if (isR) outBf[(size_t)g2*FCH + cc] = hv;
        else     skipB[(size_t)g2*FCH + cc] = hv;
      }
  }
}

// ---------------------------------------------------------------------------
// Final head: h=selu(skip); h=selu(h@Wd1+bd1); out=h@Wd2+bd2  -- OUT IS FP32
// ---------------------------------------------------------------------------
__global__ __launch_bounds__(256, 2) void final_kernel(
    const u16* __restrict__ skipB, const u16* __restrict__ BpD1, const u16* __restrict__ BpD2,
    const float* __restrict__ bd1, const float* __restrict__ bd2, float* __restrict__ outp,
    int nT8)
{
  __shared__ __align__(16) u16 ldsH[64*264];
  __shared__ __align__(16) u16 ldsH2[64*72];
  const int tid = threadIdx.x;
  const int w = tid >> 6, lane = tid & 63, q = lane >> 4, i15 = lane & 15;
  const int rb = xcd_tile(blockIdx.x, nT8) * 64;
  const int sm = tid >> 2, sseg = tid & 3;

  {
    const u16* sp = skipB + (size_t)(rb + sm)*256 + sseg*64;
    u16* dr = &ldsH[sm*264 + sseg*64];
    #pragma unroll
    for (int u = 0; u < 8; ++u) {
      uint4 raw = *reinterpret_cast<const uint4*>(sp + u*8);
      u32 rr[4] = {raw.x, raw.y, raw.z, raw.w};
      uint4 o;
      u32 oo[4];
      #pragma unroll
      for (int p = 0; p < 4; ++p) {
        float e0 = seluf(bf2f((u16)(rr[p] & 0xffffu)));
        float e1 = seluf(bf2f((u16)(rr[p] >> 16)));
        oo[p] = (u32)f2bf(e0) | ((u32)f2bf(e1) << 16);
      }
      o.x = oo[0]; o.y = oo[1]; o.z = oo[2]; o.w = oo[3];
      *reinterpret_cast<uint4*>(dr + u*8) = o;
    }
  }
  __syncthreads();

  f4v a1[4];
  #pragma unroll
  for (int mt = 0; mt < 4; ++mt) a1[mt] = (f4v){0.f,0.f,0.f,0.f};
  for (int kc = 0; kc < 8; ++kc) {
    s8v b = *reinterpret_cast<const s8v*>(BpD1 + ((size_t)(kc*4 + w)*64 + lane)*8);
    #pragma unroll
    for (int mt = 0; mt < 4; ++mt) {
      s8v af = *reinterpret_cast<const s8v*>(&ldsH[(mt*16 + i15)*264 + kc*32 + q*8]);
      a1[mt] = __builtin_amdgcn_mfma_f32_16x16x32_bf16(af, b, a1[mt], 0,0,0);
    }
  }
  const float bb1 = bd1[w*16 + i15];
  #pragma unroll
  for (int mt = 0; mt < 4; ++mt)
    #pragma unroll
    for (int r = 0; r < 4; ++r)
      ldsH2[(mt*16 + q*4 + r)*72 + w*16 + i15] = f2bf(seluf(a1[mt][r] + bb1));
  __syncthreads();

  f4v a2[4];
  #pragma unroll
  for (int mt = 0; mt < 4; ++mt) a2[mt] = (f4v){0.f,0.f,0.f,0.f};
  #pragma unroll
  for (int kc = 0; kc < 2; ++kc) {
    s8v b = *reinterpret_cast<const s8v*>(BpD2 + ((size_t)(kc*4 + w)*64 + lane)*8);
    #pragma unroll
    for (int mt = 0; mt < 4; ++mt) {
      s8v af = *reinterpret_cast<const s8v*>(&ldsH2[(mt*16 + i15)*72 + kc*32 + q*8]);
      a2[mt] = __builtin_amdgcn_mfma_f32_16x16x32_bf16(af, b, a2[mt], 0,0,0);
    }
  }
  const float bb2 = bd2[w*16 + i15];
  #pragma unroll
  for (int mt = 0; mt < 4; ++mt)
    #pragma unroll
    for (int r = 0; r < 4; ++r)
      outp[(size_t)(rb + mt*16 + q*4 + r)*64 + w*16 + i15] = a2[mt][r] + bb2;  // FP32
}

// Diagnostic sentinel (should never fire; ws proven >= 84 MB).
__global__ __launch_bounds__(256) void zero_kernel(uint4* __restrict__ outp, int n16)
{
  int i = blockIdx.x*256 + threadIdx.x;
  if (i < n16) outp[i] = (uint4){0u,0u,0u,0u};
}

// ---------------------------------------------------------------------------
extern "C" void kernel_launch(void* const* d_in, const int* in_sizes, int n_in,
                              void* d_out, int out_size, void* d_ws, size_t ws_size,
                              hipStream_t stream)
{
  (void)n_in;
  const float* x   = (const float*)d_in[0];
  const float* Wc  = (const float*)d_in[1];
  const float* Wf  = (const float*)d_in[2];
  const float* Wg  = (const float*)d_in[3];
  const float* Wr  = (const float*)d_in[4];
  const float* br  = (const float*)d_in[5];
  const float* Ws  = (const float*)d_in[6];
  const float* bs  = (const float*)d_in[7];
  const float* Wd1 = (const float*)d_in[8];
  const float* bd1 = (const float*)d_in[9];
  const float* Wd2 = (const float*)d_in[10];
  const float* bd2 = (const float*)d_in[11];

  const size_t ROWS = (size_t)in_sizes[0] / 64;     // B*T = 32768
  const int gridC = (int)(ROWS / 64);               // 512  (conv0 / final)
  const int gridL = (int)(ROWS / 32);               // 1024 (layers)
  const int nT8C = (gridC % 8 == 0) ? gridC / 8 : 0;
  const int nT8L = (gridL % 8 == 0) ? gridL / 8 : 0;

  const size_t packsB = (size_t)6248 * 512 * 2;     // 6.4 MB
  const size_t bfBuf  = ROWS * 256 * 2;             // 16.78 MB
  const size_t needB = packsB + 3*bfBuf;            // 56.7 MB

  if (ws_size < needB) {
    int n16 = (out_size * 4) / 16;                  // fp32 out
    zero_kernel<<<(n16 + 255)/256, 256, 0, stream>>>((uint4*)d_out, n16);
    return;
  }

  char* ws = (char*)d_ws;
  u16* Bp1    = (u16*)ws;            ws += (size_t)4096*512*2;
  u16* Bp2    = (u16*)ws;            ws += (size_t)2048*512*2;
  u16* Bp0    = (u16*)ws;            ws += (size_t)64*512*2;
  u16* BpD1   = (u16*)ws;            ws += (size_t)32*512*2;
  u16* BpD2   = (u16*)ws;            ws += (size_t)8*512*2;
  u16* skipB  = (u16*)ws;            ws += bfBuf;
  u16* bufA   = (u16*)ws;            ws += bfBuf;
  u16* bufB   = (u16*)ws;            ws += bfBuf;

  pack_kernel<<<1562, 256, 0, stream>>>(Wc, Wf, Wg, Wr, Ws, Wd1, Wd2,
                                        Bp1, Bp2, Bp0, BpD1, BpD2);
  conv0_kernel<<<gridC, 256, 0, stream>>>(x, bufA, Bp0, nT8C);
  u16* bufs[2] = {bufA, bufB};
  for (int i = 0; i < 8; ++i) {
    layer_kernel<<<gridL, 256, 0, stream>>>(
        bufs[i & 1], bufs[(i + 1) & 1], skipB,
        Bp1 + (size_t)i*262144, Bp2 + (size_t)i*131072,
        br + i*256, bs + i*256, 2 << i, (i == 0) ? 1 : 0, nT8L);
  }
  final_kernel<<<gridC, 256, 0, stream>>>(skipB, BpD1, BpD2, bd1, bd2,
                                          (float*)d_out, nT8C);
}

// Round 7
// 582.637 us; speedup vs baseline: 1.0261x; 1.0261x over previous
//
#include <hip/hip_runtime.h>
#include <cstdint>

typedef unsigned short u16;
typedef unsigned int u32;
typedef __attribute__((ext_vector_type(8))) short s8v;    // 8 bf16 (4 VGPRs)
typedef __attribute__((ext_vector_type(4))) float f4v;    // 16x16 MFMA acc
typedef __attribute__((ext_vector_type(16))) float f16v;  // 32x32 MFMA acc

#define FCH 256

__device__ __forceinline__ float bf2f(u16 u){ return __uint_as_float(((u32)u)<<16); }
__device__ __forceinline__ u16 f2bf(float x){
  u32 u = __float_as_uint(x);
  u += 0x7fffu + ((u>>16)&1u);
  return (u16)(u>>16);
}
__device__ __forceinline__ uint4 pack8(float4 a, float4 b){
  uint4 o;
  o.x = (u32)f2bf(a.x) | ((u32)f2bf(a.y)<<16);
  o.y = (u32)f2bf(a.z) | ((u32)f2bf(a.w)<<16);
  o.z = (u32)f2bf(b.x) | ((u32)f2bf(b.y)<<16);
  o.w = (u32)f2bf(b.z) | ((u32)f2bf(b.w)<<16);
  return o;
}
__device__ __forceinline__ float seluf(float x){
  const float sc = 1.0507009873554805f, al = 1.6732632423543772f;
  return x > 0.f ? sc*x : sc*al*(__expf(x)-1.f);
}
// Masked 16B load: AND each dword with m (m=0 zeroes the fragment).
__device__ __forceinline__ s8v ldmask(const u16* p, u32 m){
  uint4 r = *reinterpret_cast<const uint4*>(p);
  r.x &= m; r.y &= m; r.z &= m; r.w &= m;
  s8v v; *reinterpret_cast<uint4*>(&v) = r;
  return v;
}
// XCD-stripe swizzle.
__device__ __forceinline__ int xcd_tile(int bid, int nT8){
  return nT8 ? ((bid & 7) * nT8 + (bid >> 3)) : bid;
}

// ---------------------------------------------------------------------------
// Weight packing.
// Bp1/Bp2: 32-wide tiles for mfma_32x32x16: frag (kc,nt), lane l slot j =
//   B[kc*16 + (l>>5)*8 + j][nt*32 + (l&31)]   (16B/lane contiguous)
// Bp0/BpD1/BpD2: 16-wide tiles for mfma_16x16x32 (conv0/final, unchanged):
//   B[kc*32 + (l>>4)*8 + j][nt*16 + (l&15)]
// ---------------------------------------------------------------------------
__global__ __launch_bounds__(256) void pack_kernel(
    const float* __restrict__ Wc, const float* __restrict__ Wf, const float* __restrict__ Wg,
    const float* __restrict__ Wr, const float* __restrict__ Ws,
    const float* __restrict__ Wd1, const float* __restrict__ Wd2,
    u16* __restrict__ Bp1, u16* __restrict__ Bp2, u16* __restrict__ Bp0,
    u16* __restrict__ BpD1, u16* __restrict__ BpD2)
{
  int gid = blockIdx.x*256 + threadIdx.x;
  int frag = gid >> 6;
  int lane = gid & 63;
  int q = lane >> 4, i15 = lane & 15;     // 16-wide helpers
  int hi = lane >> 5, c31 = lane & 31;    // 32-wide helpers
  u16 v[8];
  u16* dst;
  if (frag < 4096) {                       // Bp1: [Wf|Wg] K=512, 32-wide tiles
    int layer = frag >> 9, rem = frag & 511;
    int kc = rem >> 4, nt = rem & 15;      // kc 0..31, nt 0..15
    int n = nt*32 + c31;
    const float* W = (n < 256) ? Wf : Wg;
    int nn = (n < 256) ? n : n - 256;
    #pragma unroll
    for (int j = 0; j < 8; ++j) {
      int k = kc*16 + hi*8 + j;
      int tap = k >> 8, cin = k & 255;
      v[j] = f2bf(W[((size_t)((layer*2 + tap)*256 + cin))*256 + nn]);
    }
    dst = Bp1 + (size_t)frag*512 + lane*8;
  } else if (frag < 6144) {                // Bp2: [Wr|Ws] K=256, 32-wide tiles
    int f = frag - 4096;
    int layer = f >> 8, rem = f & 255;
    int kc = rem >> 4, nt = rem & 15;      // kc 0..15, nt 0..15
    int n = nt*32 + c31;
    const float* W = (n < 256) ? Wr : Ws;
    int nn = (n < 256) ? n : n - 256;
    #pragma unroll
    for (int j = 0; j < 8; ++j) {
      int k = kc*16 + hi*8 + j;
      v[j] = f2bf(W[((size_t)(layer*256 + k))*256 + nn]);
    }
    dst = Bp2 + (size_t)f*512 + lane*8;
  } else if (frag < 6208) {                // Bp0: Wc K=128 (16-wide, conv0)
    int f = frag - 6144;
    int kc = f >> 4, nt = f & 15;
    int n = nt*16 + i15;
    #pragma unroll
    for (int j = 0; j < 8; ++j) {
      int k = kc*32 + q*8 + j;
      int tap = k >> 6, cin = k & 63;
      v[j] = f2bf(Wc[(size_t)(tap*64 + cin)*256 + n]);
    }
    dst = Bp0 + (size_t)f*512 + lane*8;
  } else if (frag < 6240) {                // BpD1: Wd1 [256,64] (16-wide)
    int f = frag - 6208;
    int kc = f >> 2, nt = f & 3;
    int n = nt*16 + i15;
    #pragma unroll
    for (int j = 0; j < 8; ++j) {
      int k = kc*32 + q*8 + j;
      v[j] = f2bf(Wd1[(size_t)k*64 + n]);
    }
    dst = BpD1 + (size_t)f*512 + lane*8;
  } else if (frag < 6248) {                // BpD2: Wd2 [64,64] (16-wide)
    int f = frag - 6240;
    int kc = f >> 2, nt = f & 3;
    int n = nt*16 + i15;
    #pragma unroll
    for (int j = 0; j < 8; ++j) {
      int k = kc*32 + q*8 + j;
      v[j] = f2bf(Wd2[(size_t)k*64 + n]);
    }
    dst = BpD2 + (size_t)f*512 + lane*8;
  } else return;
  uint4 o;
  o.x = (u32)v[0] | ((u32)v[1] << 16);
  o.y = (u32)v[2] | ((u32)v[3] << 16);
  o.z = (u32)v[4] | ((u32)v[5] << 16);
  o.w = (u32)v[6] | ((u32)v[7] << 16);
  *reinterpret_cast<uint4*>(dst) = o;
}

// ---------------------------------------------------------------------------
// Initial causal conv (dilation 1, no bias): out0 = [x[t-1]|x[t]] @ cat(Wc)
// ---------------------------------------------------------------------------
__global__ __launch_bounds__(256, 2) void conv0_kernel(
    const float* __restrict__ x, u16* __restrict__ outBf,
    const u16* __restrict__ Bp0, int nT8)
{
  __shared__ __align__(16) u16 ldsA[2][2048];
  const int tid = threadIdx.x;
  const int w = tid >> 6, lane = tid & 63, q = lane >> 4, i15 = lane & 15;
  const int rb = xcd_tile(blockIdx.x, nT8) * 64;
  const int sm = tid >> 2, sg = tid & 3;
  const int grow = rb + sm;
  const int tpos = grow & 4095;
  const int sunit = ((sm >> 4)*64 + sg*16 + ((sm & 15) ^ (sg << 1))) * 8;
  const int runit = (q*16 + (i15 ^ (q << 1))) * 8;

  f4v acc[4][4];
  #pragma unroll
  for (int jj = 0; jj < 4; ++jj)
    #pragma unroll
    for (int mt = 0; mt < 4; ++mt)
      acc[jj][mt] = (f4v){0.f,0.f,0.f,0.f};

  float4 f0 = {0.f,0.f,0.f,0.f}, f1 = {0.f,0.f,0.f,0.f};
  if (tpos >= 1) {
    const float* px = x + (size_t)(grow-1)*64 + sg*8;
    f0 = *reinterpret_cast<const float4*>(px);
    f1 = *reinterpret_cast<const float4*>(px + 4);
  }
  *reinterpret_cast<uint4*>(&ldsA[0][sunit]) = pack8(f0, f1);
  s8v bcur[4], bnxt[4];
  #pragma unroll
  for (int jj = 0; jj < 4; ++jj)
    bcur[jj] = *reinterpret_cast<const s8v*>(Bp0 + ((size_t)(w + 4*jj)*64 + lane)*8);
  __syncthreads();

  for (int kc = 0; kc < 4; ++kc) {
    const int cur = kc & 1;
    uint4 an = {0u,0u,0u,0u};
    if (kc < 3) {
      int kg = (kc+1)*32 + sg*8;
      int tap = kg >> 6, col = kg & 63;
      float4 g0 = {0.f,0.f,0.f,0.f}, g1 = {0.f,0.f,0.f,0.f};
      if (tap) {
        const float* px = x + (size_t)grow*64 + col;
        g0 = *reinterpret_cast<const float4*>(px);
        g1 = *reinterpret_cast<const float4*>(px + 4);
      } else if (tpos >= 1) {
        const float* px = x + (size_t)(grow-1)*64 + col;
        g0 = *reinterpret_cast<const float4*>(px);
        g1 = *reinterpret_cast<const float4*>(px + 4);
      }
      an = pack8(g0, g1);
      #pragma unroll
      for (int jj = 0; jj < 4; ++jj)
        bnxt[jj] = *reinterpret_cast<const s8v*>(Bp0 + (((size_t)(kc+1)*16 + (w + 4*jj))*64 + lane)*8);
    }
    s8v af[4];
    #pragma unroll
    for (int mt = 0; mt < 4; ++mt)
      af[mt] = *reinterpret_cast<const s8v*>(&ldsA[cur][mt*512 + runit]);
    #pragma unroll
    for (int jj = 0; jj < 4; ++jj)
      #pragma unroll
      for (int mt = 0; mt < 4; ++mt)
        acc[jj][mt] = __builtin_amdgcn_mfma_f32_16x16x32_bf16(af[mt], bcur[jj], acc[jj][mt], 0,0,0);
    if (kc < 3) {
      *reinterpret_cast<uint4*>(&ldsA[cur ^ 1][sunit]) = an;
      #pragma unroll
      for (int jj = 0; jj < 4; ++jj) bcur[jj] = bnxt[jj];
    }
    __syncthreads();
  }

  #pragma unroll
  for (int jj = 0; jj < 4; ++jj) {
    const int cc = (w + 4*jj)*16 + i15;
    #pragma unroll
    for (int mt = 0; mt < 4; ++mt)
      #pragma unroll
      for (int r = 0; r < 4; ++r) {
        const int g2 = rb + mt*16 + q*4 + r;
        outBf[(size_t)g2*FCH + cc] = f2bf(acc[jj][mt][r]);
      }
  }
}

// ---------------------------------------------------------------------------
// One WaveNet residual layer. M=32, 256 thr, 1024 blocks, R5 pipeline but on
// mfma_f32_32x32x16_bf16: 192 MFMA/wave (vs 384), ~17% fewer matrix cycles,
// same operand bytes. A-frag: lane(hi=l>>5,c31=l&31) -> 16B at
// inBf[row=rb+c31][kc*16 + hi*8]. C/D: col=l&31, row=(r&3)+8*(r>>2)+4*hi.
// acc = 4 x f32x16 = 64 AGPR; launch_bounds(256,3) (R6 showed 4 waves spills).
// ---------------------------------------------------------------------------
__global__ __launch_bounds__(256, 3) void layer_kernel(
    const u16* __restrict__ inBf, u16* __restrict__ outBf,
    u16* __restrict__ skipB,
    const u16* __restrict__ Bp1, const u16* __restrict__ Bp2,
    const float* __restrict__ br, const float* __restrict__ bs,
    int dil, int first, int nT8)
{
  __shared__ __align__(16) u16 ldsZ[32*264];     // 16.9 KB
  const int tid = threadIdx.x;
  const int w = tid >> 6, lane = tid & 63, hi = lane >> 5, c31 = lane & 31;
  const int rb = xcd_tile(blockIdx.x, nT8) * 32;

  // per-wave N-tiles (32-wide): jj 0,1 -> F/R tiles nt=2w+jj; jj 2,3 -> G/S at nt=8+2w+(jj-2)
  f16v acc[4];
  #pragma unroll
  for (int jj = 0; jj < 4; ++jj)
    #pragma unroll
    for (int r = 0; r < 16; ++r) acc[jj][r] = 0.f;

  // ---------------- stage 1: pipelined, A direct from global ----------------
  {
    const int row = rb + c31;
    const bool v = (row & 4095) >= dil;
    const u16* a0 = inBf + (size_t)(v ? row - dil : row)*FCH + hi*8;  // tap0
    const u16* a1 = inBf + (size_t)row*FCH + hi*8;                    // tap1
    const u32 am = v ? 0xffffffffu : 0u;

    s8v bb[2][4], aa[2];
    #pragma unroll
    for (int jj = 0; jj < 4; ++jj) {
      const int nt = (jj < 2) ? (2*w + jj) : (8 + 2*w + (jj - 2));
      bb[0][jj] = *reinterpret_cast<const s8v*>(Bp1 + ((size_t)nt*64 + lane)*8);
    }
    aa[0] = ldmask(a0, am);

    #pragma unroll
    for (int kc = 0; kc < 32; ++kc) {
      const int cur = kc & 1, nxt = cur ^ 1;
      if (kc + 1 < 32) {
        const int kn = kc + 1;
        #pragma unroll
        for (int jj = 0; jj < 4; ++jj) {
          const int nt = (jj < 2) ? (2*w + jj) : (8 + 2*w + (jj - 2));
          bb[nxt][jj] = *reinterpret_cast<const s8v*>(Bp1 + (((size_t)kn*16 + nt)*64 + lane)*8);
        }
        if (kn < 16) aa[nxt] = ldmask(a0 + kn*16, am);
        else         aa[nxt] = *reinterpret_cast<const s8v*>(a1 + (kn - 16)*16);
      }
      __builtin_amdgcn_s_setprio(1);
      #pragma unroll
      for (int jj = 0; jj < 4; ++jj)
        acc[jj] = __builtin_amdgcn_mfma_f32_32x32x16_bf16(aa[cur], bb[cur][jj], acc[jj], 0,0,0);
      __builtin_amdgcn_s_setprio(0);
    }
  }

  // -------- issue stage-2 kc=0 B loads now (latency hides under exp) --------
  s8v s2b[2][4];
  #pragma unroll
  for (int jj = 0; jj < 4; ++jj) {
    const int nt = (jj < 2) ? (2*w + jj) : (8 + 2*w + (jj - 2));
    s2b[0][jj] = *reinterpret_cast<const s8v*>(Bp2 + ((size_t)nt*64 + lane)*8);
  }

  // ---------------- activation: Z -> LDS (C-layout -> row-major) ------------
  #pragma unroll
  for (int jj = 0; jj < 2; ++jj) {
    const int colb = (2*w + jj)*32 + c31;
    #pragma unroll
    for (int r = 0; r < 16; ++r) {
      const int rowid = (r & 3) + 8*(r >> 2) + 4*hi;
      float f = acc[jj][r];
      float g = acc[jj+2][r];
      float z = (1.f - 2.f/(__expf(2.f*f) + 1.f)) * (1.f/(1.f + __expf(-g)));
      ldsZ[rowid*264 + colb] = f2bf(z);
    }
  }
  // zero acc for stage 2 (residual/skip/bias added in epilogue, f32)
  #pragma unroll
  for (int jj = 0; jj < 4; ++jj)
    #pragma unroll
    for (int r = 0; r < 16; ++r) acc[jj][r] = 0.f;
  __syncthreads();   // the ONLY barrier in this kernel

  // ---------------- stage 2 (pipelined: B global dist-1, A LDS dist-1) ------
  {
    s8v zf[2];
    zf[0] = *reinterpret_cast<const s8v*>(&ldsZ[c31*264 + hi*8]);
    #pragma unroll
    for (int kc = 0; kc < 16; ++kc) {
      const int cur = kc & 1, nxt = cur ^ 1;
      if (kc + 1 < 16) {
        const int kn = kc + 1;
        #pragma unroll
        for (int jj = 0; jj < 4; ++jj) {
          const int nt = (jj < 2) ? (2*w + jj) : (8 + 2*w + (jj - 2));
          s2b[nxt][jj] = *reinterpret_cast<const s8v*>(Bp2 + (((size_t)kn*16 + nt)*64 + lane)*8);
        }
        zf[nxt] = *reinterpret_cast<const s8v*>(&ldsZ[c31*264 + kn*16 + hi*8]);
      }
      __builtin_amdgcn_s_setprio(1);
      #pragma unroll
      for (int jj = 0; jj < 4; ++jj)
        acc[jj] = __builtin_amdgcn_mfma_f32_32x32x16_bf16(zf[cur], s2b[cur][jj], acc[jj], 0,0,0);
      __builtin_amdgcn_s_setprio(0);
    }
  }

  // ---------------- epilogue: load residual/skip, add bias in f32, store ----
  u16 resv[2][16], skv[2][16];
  #pragma unroll
  for (int jj = 0; jj < 2; ++jj) {
    const int cc = (2*w + jj)*32 + c31;
    #pragma unroll
    for (int r = 0; r < 16; ++r) {
      const int rowid = (r & 3) + 8*(r >> 2) + 4*hi;
      resv[jj][r] = inBf[(size_t)(rb + rowid)*FCH + cc];
    }
  }
  if (!first) {
    #pragma unroll
    for (int jj = 0; jj < 2; ++jj) {
      const int cc = (2*w + jj)*32 + c31;
      #pragma unroll
      for (int r = 0; r < 16; ++r) {
        const int rowid = (r & 3) + 8*(r >> 2) + 4*hi;
        skv[jj][r] = skipB[(size_t)(rb + rowid)*FCH + cc];
      }
    }
  }
  #pragma unroll
  for (int jj = 0; jj < 4; ++jj) {
    const bool isR = (jj < 2);
    const int cc = (2*w + (isR ? jj : jj - 2))*32 + c31;
    const float bias = isR ? br[cc] : bs[cc];
    #pragma unroll
    for (int r = 0; r < 16; ++r) {
      const int rowid = (r & 3) + 8*(r >> 2) + 4*hi;
      const int g2 = rb + rowid;
      float vv = acc[jj][r] + bias;
      if (isR) vv += bf2f(resv[jj][r]);
      else if (!first) vv += bf2f(skv[jj-2][r]);
      u16 hv = f2bf(vv);
      if (isR) outBf[(size_t)g2*FCH + cc] = hv;
      else     skipB[(size_t)g2*FCH + cc] = hv;
    }
  }
}

// ---------------------------------------------------------------------------
// Final head: h=selu(skip); h=selu(h@Wd1+bd1); out=h@Wd2+bd2  -- OUT IS FP32
// ---------------------------------------------------------------------------
__global__ __launch_bounds__(256, 2) void final_kernel(
    const u16* __restrict__ skipB, const u16* __restrict__ BpD1, const u16* __restrict__ BpD2,
    const float* __restrict__ bd1, const float* __restrict__ bd2, float* __restrict__ outp,
    int nT8)
{
  __shared__ __align__(16) u16 ldsH[64*264];
  __shared__ __align__(16) u16 ldsH2[64*72];
  const int tid = threadIdx.x;
  const int w = tid >> 6, lane = tid & 63, q = lane >> 4, i15 = lane & 15;
  const int rb = xcd_tile(blockIdx.x, nT8) * 64;
  const int sm = tid >> 2, sseg = tid & 3;

  {
    const u16* sp = skipB + (size_t)(rb + sm)*256 + sseg*64;
    u16* dr = &ldsH[sm*264 + sseg*64];
    #pragma unroll
    for (int u = 0; u < 8; ++u) {
      uint4 raw = *reinterpret_cast<const uint4*>(sp + u*8);
      u32 rr[4] = {raw.x, raw.y, raw.z, raw.w};
      uint4 o;
      u32 oo[4];
      #pragma unroll
      for (int p = 0; p < 4; ++p) {
        float e0 = seluf(bf2f((u16)(rr[p] & 0xffffu)));
        float e1 = seluf(bf2f((u16)(rr[p] >> 16)));
        oo[p] = (u32)f2bf(e0) | ((u32)f2bf(e1) << 16);
      }
      o.x = oo[0]; o.y = oo[1]; o.z = oo[2]; o.w = oo[3];
      *reinterpret_cast<uint4*>(dr + u*8) = o;
    }
  }
  __syncthreads();

  f4v a1[4];
  #pragma unroll
  for (int mt = 0; mt < 4; ++mt) a1[mt] = (f4v){0.f,0.f,0.f,0.f};
  for (int kc = 0; kc < 8; ++kc) {
    s8v b = *reinterpret_cast<const s8v*>(BpD1 + ((size_t)(kc*4 + w)*64 + lane)*8);
    #pragma unroll
    for (int mt = 0; mt < 4; ++mt) {
      s8v af = *reinterpret_cast<const s8v*>(&ldsH[(mt*16 + i15)*264 + kc*32 + q*8]);
      a1[mt] = __builtin_amdgcn_mfma_f32_16x16x32_bf16(af, b, a1[mt], 0,0,0);
    }
  }
  const float bb1 = bd1[w*16 + i15];
  #pragma unroll
  for (int mt = 0; mt < 4; ++mt)
    #pragma unroll
    for (int r = 0; r < 4; ++r)
      ldsH2[(mt*16 + q*4 + r)*72 + w*16 + i15] = f2bf(seluf(a1[mt][r] + bb1));
  __syncthreads();

  f4v a2[4];
  #pragma unroll
  for (int mt = 0; mt < 4; ++mt) a2[mt] = (f4v){0.f,0.f,0.f,0.f};
  #pragma unroll
  for (int kc = 0; kc < 2; ++kc) {
    s8v b = *reinterpret_cast<const s8v*>(BpD2 + ((size_t)(kc*4 + w)*64 + lane)*8);
    #pragma unroll
    for (int mt = 0; mt < 4; ++mt) {
      s8v af = *reinterpret_cast<const s8v*>(&ldsH2[(mt*16 + i15)*72 + kc*32 + q*8]);
      a2[mt] = __builtin_amdgcn_mfma_f32_16x16x32_bf16(af, b, a2[mt], 0,0,0);
    }
  }
  const float bb2 = bd2[w*16 + i15];
  #pragma unroll
  for (int mt = 0; mt < 4; ++mt)
    #pragma unroll
    for (int r = 0; r < 4; ++r)
      outp[(size_t)(rb + mt*16 + q*4 + r)*64 + w*16 + i15] = a2[mt][r] + bb2;  // FP32
}

// Diagnostic sentinel (should never fire; ws proven >= 84 MB).
__global__ __launch_bounds__(256) void zero_kernel(uint4* __restrict__ outp, int n16)
{
  int i = blockIdx.x*256 + threadIdx.x;
  if (i < n16) outp[i] = (uint4){0u,0u,0u,0u};
}

// ---------------------------------------------------------------------------
extern "C" void kernel_launch(void* const* d_in, const int* in_sizes, int n_in,
                              void* d_out, int out_size, void* d_ws, size_t ws_size,
                              hipStream_t stream)
{
  (void)n_in;
  const float* x   = (const float*)d_in[0];
  const float* Wc  = (const float*)d_in[1];
  const float* Wf  = (const float*)d_in[2];
  const float* Wg  = (const float*)d_in[3];
  const float* Wr  = (const float*)d_in[4];
  const float* br  = (const float*)d_in[5];
  const float* Ws  = (const float*)d_in[6];
  const float* bs  = (const float*)d_in[7];
  const float* Wd1 = (const float*)d_in[8];
  const float* bd1 = (const float*)d_in[9];
  const float* Wd2 = (const float*)d_in[10];
  const float* bd2 = (const float*)d_in[11];

  const size_t ROWS = (size_t)in_sizes[0] / 64;     // B*T = 32768
  const int gridC = (int)(ROWS / 64);               // 512  (conv0 / final)
  const int gridL = (int)(ROWS / 32);               // 1024 (layers)
  const int nT8C = (gridC % 8 == 0) ? gridC / 8 : 0;
  const int nT8L = (gridL % 8 == 0) ? gridL / 8 : 0;

  const size_t packsB = (size_t)6248 * 512 * 2;     // 6.4 MB
  const size_t bfBuf  = ROWS * 256 * 2;             // 16.78 MB
  const size_t needB = packsB + 3*bfBuf;            // 56.7 MB

  if (ws_size < needB) {
    int n16 = (out_size * 4) / 16;                  // fp32 out
    zero_kernel<<<(n16 + 255)/256, 256, 0, stream>>>((uint4*)d_out, n16);
    return;
  }

  char* ws = (char*)d_ws;
  u16* Bp1    = (u16*)ws;            ws += (size_t)4096*512*2;
  u16* Bp2    = (u16*)ws;            ws += (size_t)2048*512*2;
  u16* Bp0    = (u16*)ws;            ws += (size_t)64*512*2;
  u16* BpD1   = (u16*)ws;            ws += (size_t)32*512*2;
  u16* BpD2   = (u16*)ws;            ws += (size_t)8*512*2;
  u16* skipB  = (u16*)ws;            ws += bfBuf;
  u16* bufA   = (u16*)ws;            ws += bfBuf;
  u16* bufB   = (u16*)ws;            ws += bfBuf;

  pack_kernel<<<1562, 256, 0, stream>>>(Wc, Wf, Wg, Wr, Ws, Wd1, Wd2,
                                        Bp1, Bp2, Bp0, BpD1, BpD2);
  conv0_kernel<<<gridC, 256, 0, stream>>>(x, bufA, Bp0, nT8C);
  u16* bufs[2] = {bufA, bufB};
  for (int i = 0; i < 8; ++i) {
    layer_kernel<<<gridL, 256, 0, stream>>>(
        bufs[i & 1], bufs[(i + 1) & 1], skipB,
        Bp1 + (size_t)i*262144, Bp2 + (size_t)i*131072,
        br + i*256, bs + i*256, 2 << i, (i == 0) ? 1 : 0, nT8L);
  }
  final_kernel<<<gridC, 256, 0, stream>>>(skipB, BpD1, BpD2, bd1, bd2,
                                          (float*)d_out, nT8C);
}

// Round 8
// 491.880 us; speedup vs baseline: 1.2154x; 1.1845x over previous
//
#include <hip/hip_runtime.h>
#include <cstdint>

typedef unsigned short u16;
typedef unsigned int u32;
typedef __attribute__((ext_vector_type(8))) short s8v;   // 8 bf16 (4 VGPRs)
typedef __attribute__((ext_vector_type(4))) float f4v;   // MFMA acc

#define FCH 256

__device__ __forceinline__ float bf2f(u16 u){ return __uint_as_float(((u32)u)<<16); }
__device__ __forceinline__ u16 f2bf(float x){
  u32 u = __float_as_uint(x);
  u += 0x7fffu + ((u>>16)&1u);
  return (u16)(u>>16);
}
__device__ __forceinline__ uint4 pack8(float4 a, float4 b){
  uint4 o;
  o.x = (u32)f2bf(a.x) | ((u32)f2bf(a.y)<<16);
  o.y = (u32)f2bf(a.z) | ((u32)f2bf(a.w)<<16);
  o.z = (u32)f2bf(b.x) | ((u32)f2bf(b.y)<<16);
  o.w = (u32)f2bf(b.z) | ((u32)f2bf(b.w)<<16);
  return o;
}
__device__ __forceinline__ float seluf(float x){
  const float sc = 1.0507009873554805f, al = 1.6732632423543772f;
  return x > 0.f ? sc*x : sc*al*(__expf(x)-1.f);
}
// Masked 16B load: AND each dword with m (m=0 zeroes the fragment).
__device__ __forceinline__ s8v ldmask(const u16* p, u32 m){
  uint4 r = *reinterpret_cast<const uint4*>(p);
  r.x &= m; r.y &= m; r.z &= m; r.w &= m;
  s8v v; *reinterpret_cast<uint4*>(&v) = r;
  return v;
}
// XCD-stripe swizzle.
__device__ __forceinline__ int xcd_tile(int bid, int nT8){
  return nT8 ? ((bid & 7) * nT8 + (bid >> 3)) : bid;
}

// ---------------------------------------------------------------------------
// Weight packing (fp32 -> bf16 fragments): lane l slot j of frag (kc,nt) =
// B[kc*32 + (l>>4)*8 + j][nt*16 + (l&15)]  (16B/lane contiguous)
// ---------------------------------------------------------------------------
__global__ __launch_bounds__(256) void pack_kernel(
    const float* __restrict__ Wc, const float* __restrict__ Wf, const float* __restrict__ Wg,
    const float* __restrict__ Wr, const float* __restrict__ Ws,
    const float* __restrict__ Wd1, const float* __restrict__ Wd2,
    u16* __restrict__ Bp1, u16* __restrict__ Bp2, u16* __restrict__ Bp0,
    u16* __restrict__ BpD1, u16* __restrict__ BpD2)
{
  int gid = blockIdx.x*256 + threadIdx.x;
  int frag = gid >> 6;
  int lane = gid & 63;
  int q = lane >> 4, i15 = lane & 15;
  u16 v[8];
  u16* dst;
  if (frag < 4096) {                       // Bp1: [Wf|Wg] K=512 (tap-major)
    int layer = frag >> 9, rem = frag & 511;
    int kc = rem >> 5, nt = rem & 31;
    int n = nt*16 + i15;
    const float* W = (n < 256) ? Wf : Wg;
    int nn = (n < 256) ? n : n - 256;
    #pragma unroll
    for (int j = 0; j < 8; ++j) {
      int k = kc*32 + q*8 + j;
      int tap = k >> 8, cin = k & 255;
      v[j] = f2bf(W[((size_t)((layer*2 + tap)*256 + cin))*256 + nn]);
    }
    dst = Bp1 + (size_t)frag*512 + lane*8;
  } else if (frag < 6144) {                // Bp2: [Wr|Ws] K=256
    int f = frag - 4096;
    int layer = f >> 8, rem = f & 255;
    int kc = rem >> 5, nt = rem & 31;
    int n = nt*16 + i15;
    const float* W = (n < 256) ? Wr : Ws;
    int nn = (n < 256) ? n : n - 256;
    #pragma unroll
    for (int j = 0; j < 8; ++j) {
      int k = kc*32 + q*8 + j;
      v[j] = f2bf(W[((size_t)(layer*256 + k))*256 + nn]);
    }
    dst = Bp2 + (size_t)f*512 + lane*8;
  } else if (frag < 6208) {                // Bp0: Wc K=128
    int f = frag - 6144;
    int kc = f >> 4, nt = f & 15;
    int n = nt*16 + i15;
    #pragma unroll
    for (int j = 0; j < 8; ++j) {
      int k = kc*32 + q*8 + j;
      int tap = k >> 6, cin = k & 63;
      v[j] = f2bf(Wc[(size_t)(tap*64 + cin)*256 + n]);
    }
    dst = Bp0 + (size_t)f*512 + lane*8;
  } else if (frag < 6240) {                // BpD1: Wd1 [256,64]
    int f = frag - 6208;
    int kc = f >> 2, nt = f & 3;
    int n = nt*16 + i15;
    #pragma unroll
    for (int j = 0; j < 8; ++j) {
      int k = kc*32 + q*8 + j;
      v[j] = f2bf(Wd1[(size_t)k*64 + n]);
    }
    dst = BpD1 + (size_t)f*512 + lane*8;
  } else if (frag < 6248) {                // BpD2: Wd2 [64,64]
    int f = frag - 6240;
    int kc = f >> 2, nt = f & 3;
    int n = nt*16 + i15;
    #pragma unroll
    for (int j = 0; j < 8; ++j) {
      int k = kc*32 + q*8 + j;
      v[j] = f2bf(Wd2[(size_t)k*64 + n]);
    }
    dst = BpD2 + (size_t)f*512 + lane*8;
  } else return;
  uint4 o;
  o.x = (u32)v[0] | ((u32)v[1] << 16);
  o.y = (u32)v[2] | ((u32)v[3] << 16);
  o.z = (u32)v[4] | ((u32)v[5] << 16);
  o.w = (u32)v[6] | ((u32)v[7] << 16);
  *reinterpret_cast<uint4*>(dst) = o;
}

// ---------------------------------------------------------------------------
// Initial causal conv (dilation 1, no bias): out0 = [x[t-1]|x[t]] @ cat(Wc)
// ---------------------------------------------------------------------------
__global__ __launch_bounds__(256, 2) void conv0_kernel(
    const float* __restrict__ x, u16* __restrict__ outBf,
    const u16* __restrict__ Bp0, int nT8)
{
  __shared__ __align__(16) u16 ldsA[2][2048];
  const int tid = threadIdx.x;
  const int w = tid >> 6, lane = tid & 63, q = lane >> 4, i15 = lane & 15;
  const int rb = xcd_tile(blockIdx.x, nT8) * 64;
  const int sm = tid >> 2, sg = tid & 3;
  const int grow = rb + sm;
  const int tpos = grow & 4095;
  const int sunit = ((sm >> 4)*64 + sg*16 + ((sm & 15) ^ (sg << 1))) * 8;
  const int runit = (q*16 + (i15 ^ (q << 1))) * 8;

  f4v acc[4][4];
  #pragma unroll
  for (int jj = 0; jj < 4; ++jj)
    #pragma unroll
    for (int mt = 0; mt < 4; ++mt)
      acc[jj][mt] = (f4v){0.f,0.f,0.f,0.f};

  float4 f0 = {0.f,0.f,0.f,0.f}, f1 = {0.f,0.f,0.f,0.f};
  if (tpos >= 1) {
    const float* px = x + (size_t)(grow-1)*64 + sg*8;
    f0 = *reinterpret_cast<const float4*>(px);
    f1 = *reinterpret_cast<const float4*>(px + 4);
  }
  *reinterpret_cast<uint4*>(&ldsA[0][sunit]) = pack8(f0, f1);
  s8v bcur[4], bnxt[4];
  #pragma unroll
  for (int jj = 0; jj < 4; ++jj)
    bcur[jj] = *reinterpret_cast<const s8v*>(Bp0 + ((size_t)(w + 4*jj)*64 + lane)*8);
  __syncthreads();

  for (int kc = 0; kc < 4; ++kc) {
    const int cur = kc & 1;
    uint4 an = {0u,0u,0u,0u};
    if (kc < 3) {
      int kg = (kc+1)*32 + sg*8;
      int tap = kg >> 6, col = kg & 63;
      float4 g0 = {0.f,0.f,0.f,0.f}, g1 = {0.f,0.f,0.f,0.f};
      if (tap) {
        const float* px = x + (size_t)grow*64 + col;
        g0 = *reinterpret_cast<const float4*>(px);
        g1 = *reinterpret_cast<const float4*>(px + 4);
      } else if (tpos >= 1) {
        const float* px = x + (size_t)(grow-1)*64 + col;
        g0 = *reinterpret_cast<const float4*>(px);
        g1 = *reinterpret_cast<const float4*>(px + 4);
      }
      an = pack8(g0, g1);
      #pragma unroll
      for (int jj = 0; jj < 4; ++jj)
        bnxt[jj] = *reinterpret_cast<const s8v*>(Bp0 + (((size_t)(kc+1)*16 + (w + 4*jj))*64 + lane)*8);
    }
    s8v af[4];
    #pragma unroll
    for (int mt = 0; mt < 4; ++mt)
      af[mt] = *reinterpret_cast<const s8v*>(&ldsA[cur][mt*512 + runit]);
    #pragma unroll
    for (int jj = 0; jj < 4; ++jj)
      #pragma unroll
      for (int mt = 0; mt < 4; ++mt)
        acc[jj][mt] = __builtin_amdgcn_mfma_f32_16x16x32_bf16(af[mt], bcur[jj], acc[jj][mt], 0,0,0);
    if (kc < 3) {
      *reinterpret_cast<uint4*>(&ldsA[cur ^ 1][sunit]) = an;
      #pragma unroll
      for (int jj = 0; jj < 4; ++jj) bcur[jj] = bnxt[jj];
    }
    __syncthreads();
  }

  #pragma unroll
  for (int jj = 0; jj < 4; ++jj) {
    const int cc = (w + 4*jj)*16 + i15;
    #pragma unroll
    for (int mt = 0; mt < 4; ++mt)
      #pragma unroll
      for (int r = 0; r < 4; ++r) {
        const int g2 = rb + mt*16 + q*4 + r;
        outBf[(size_t)g2*FCH + cc] = f2bf(acc[jj][mt][r]);
      }
  }
}

// ---------------------------------------------------------------------------
// One WaveNet residual layer. R5 structure (M=32, 256 thr, 1024 blocks,
// 16x16x32 MFMA, one barrier) with HALF-CHUNK DIST-2 B prefetch:
// 32 steps of {4 B-frags, 8 MFMA}; B issued 2 steps (~140cy + 3-wave overlap)
// ahead of consume, covering the ~200-300cy L2 latency that R5's dist-1
// (~80cy cover) exposed. bb[3][4]=48 VGPR (vs R5 bb[2][8]=64) keeps total
// ~153 regs -> still 3 waves/SIMD. A issued one full chunk (2 steps) ahead.
// ---------------------------------------------------------------------------
__global__ __launch_bounds__(256, 3) void layer_kernel(
    const u16* __restrict__ inBf, u16* __restrict__ outBf,
    u16* __restrict__ skipB,
    const u16* __restrict__ Bp1, const u16* __restrict__ Bp2,
    const float* __restrict__ br, const float* __restrict__ bs,
    int dil, int first, int nT8)
{
  __shared__ __align__(16) u16 ldsZ[32*264];     // 16.9 KB
  const int tid = threadIdx.x;
  const int w = tid >> 6, lane = tid & 63, q = lane >> 4, i15 = lane & 15;
  const int rb = xcd_tile(blockIdx.x, nT8) * 32;

  f4v acc[8][2];   // [jj: nt=w+4*jj][mt]
  #pragma unroll
  for (int jj = 0; jj < 8; ++jj)
    #pragma unroll
    for (int mt = 0; mt < 2; ++mt)
      acc[jj][mt] = (f4v){0.f,0.f,0.f,0.f};

  // ---------------- stage 1: half-chunk dist-2 pipeline ---------------------
  {
    const u16* a0p[2];   // tap0: row t-dil (safe addr; mask zeroes invalid)
    const u16* a1p[2];   // tap1: row t
    u32 am[2];
    #pragma unroll
    for (int mt = 0; mt < 2; ++mt) {
      const int row = rb + mt*16 + i15;
      const bool v = (row & 4095) >= dil;
      a0p[mt] = inBf + (size_t)(v ? row - dil : row)*FCH + q*8;
      a1p[mt] = inBf + (size_t)row*FCH + q*8;
      am[mt]  = v ? 0xffffffffu : 0u;
    }

    s8v bb[3][4], aa[2][2];
    // prologue: B for steps 0,1 (chunk 0, halves 0/1); A for chunk 0
    #pragma unroll
    for (int j2 = 0; j2 < 4; ++j2) {
      bb[0][j2] = *reinterpret_cast<const s8v*>(Bp1 + ((size_t)(w + 4*j2)*64 + lane)*8);
      bb[1][j2] = *reinterpret_cast<const s8v*>(Bp1 + ((size_t)(w + 16 + 4*j2)*64 + lane)*8);
    }
    #pragma unroll
    for (int mt = 0; mt < 2; ++mt)
      aa[0][mt] = ldmask(a0p[mt], am[mt]);

    #pragma unroll
    for (int s = 0; s < 32; ++s) {
      const int kc = s >> 1, h = s & 1;
      if (s + 2 < 32) {
        const int sp = s + 2, kcp = sp >> 1, hp = sp & 1;
        #pragma unroll
        for (int j2 = 0; j2 < 4; ++j2)
          bb[sp % 3][j2] = *reinterpret_cast<const s8v*>(
              Bp1 + (((size_t)kcp*32 + (w + 16*hp + 4*j2))*64 + lane)*8);
        if (hp == 0) {   // step sp starts chunk kcp: issue its A (2 steps early)
          if (kcp < 8) {
            #pragma unroll
            for (int mt = 0; mt < 2; ++mt)
              aa[kcp & 1][mt] = ldmask(a0p[mt] + kcp*32, am[mt]);
          } else {
            #pragma unroll
            for (int mt = 0; mt < 2; ++mt)
              aa[kcp & 1][mt] = *reinterpret_cast<const s8v*>(a1p[mt] + (kcp - 8)*32);
          }
        }
      }
      __builtin_amdgcn_s_setprio(1);
      #pragma unroll
      for (int j2 = 0; j2 < 4; ++j2)
        #pragma unroll
        for (int mt = 0; mt < 2; ++mt)
          acc[h*4 + j2][mt] = __builtin_amdgcn_mfma_f32_16x16x32_bf16(
              aa[kc & 1][mt], bb[s % 3][j2], acc[h*4 + j2][mt], 0,0,0);
      __builtin_amdgcn_s_setprio(0);
    }
  }

  // -------- issue stage-2 steps 0,1 B loads now (latency hides under exp) ---
  s8v s2b[3][4];
  #pragma unroll
  for (int j2 = 0; j2 < 4; ++j2) {
    s2b[0][j2] = *reinterpret_cast<const s8v*>(Bp2 + ((size_t)(w + 4*j2)*64 + lane)*8);
    s2b[1][j2] = *reinterpret_cast<const s8v*>(Bp2 + ((size_t)(w + 16 + 4*j2)*64 + lane)*8);
  }

  // ---------------- activation: Z -> LDS (C-layout -> row-major) ------------
  #pragma unroll
  for (int jj = 0; jj < 4; ++jj) {
    const int colb = (w + 4*jj)*16 + i15;
    #pragma unroll
    for (int mt = 0; mt < 2; ++mt)
      #pragma unroll
      for (int r = 0; r < 4; ++r) {
        float f = acc[jj][mt][r];
        float g = acc[jj+4][mt][r];
        float z = (1.f - 2.f/(__expf(2.f*f) + 1.f)) * (1.f/(1.f + __expf(-g)));
        ldsZ[(mt*16 + q*4 + r)*264 + colb] = f2bf(z);
      }
  }
  // zero acc for stage 2 (residual/skip/bias added in epilogue, f32)
  #pragma unroll
  for (int jj = 0; jj < 8; ++jj)
    #pragma unroll
    for (int mt = 0; mt < 2; ++mt)
      acc[jj][mt] = (f4v){0.f,0.f,0.f,0.f};
  __syncthreads();   // the ONLY barrier in this kernel

  // ---------------- stage 2: half-chunk dist-2 (B global, A LDS) ------------
  {
    s8v zf[2][2];
    #pragma unroll
    for (int mt = 0; mt < 2; ++mt)
      zf[0][mt] = *reinterpret_cast<const s8v*>(&ldsZ[(mt*16 + i15)*264 + q*8]);
    #pragma unroll
    for (int s = 0; s < 16; ++s) {
      const int kc = s >> 1, h = s & 1;
      if (s + 2 < 16) {
        const int sp = s + 2, kcp = sp >> 1, hp = sp & 1;
        #pragma unroll
        for (int j2 = 0; j2 < 4; ++j2)
          s2b[sp % 3][j2] = *reinterpret_cast<const s8v*>(
              Bp2 + (((size_t)kcp*32 + (w + 16*hp + 4*j2))*64 + lane)*8);
        if (hp == 0) {
          #pragma unroll
          for (int mt = 0; mt < 2; ++mt)
            zf[kcp & 1][mt] = *reinterpret_cast<const s8v*>(&ldsZ[(mt*16 + i15)*264 + kcp*32 + q*8]);
        }
      }
      __builtin_amdgcn_s_setprio(1);
      #pragma unroll
      for (int j2 = 0; j2 < 4; ++j2)
        #pragma unroll
        for (int mt = 0; mt < 2; ++mt)
          acc[h*4 + j2][mt] = __builtin_amdgcn_mfma_f32_16x16x32_bf16(
              zf[kc & 1][mt], s2b[s % 3][j2], acc[h*4 + j2][mt], 0,0,0);
      __builtin_amdgcn_s_setprio(0);
    }
  }

  // ---------------- epilogue: load residual/skip, add bias in f32, store ----
  u16 resv[4][2][4], skv[4][2][4];
  #pragma unroll
  for (int jj = 0; jj < 4; ++jj) {
    const int cc = (w + 4*jj)*16 + i15;
    #pragma unroll
    for (int mt = 0; mt < 2; ++mt)
      #pragma unroll
      for (int r = 0; r < 4; ++r)
        resv[jj][mt][r] = inBf[(size_t)(rb + mt*16 + q*4 + r)*FCH + cc];
  }
  if (!first) {
    #pragma unroll
    for (int jj = 0; jj < 4; ++jj) {
      const int cc = (w + 4*jj)*16 + i15;
      #pragma unroll
      for (int mt = 0; mt < 2; ++mt)
        #pragma unroll
        for (int r = 0; r < 4; ++r)
          skv[jj][mt][r] = skipB[(size_t)(rb + mt*16 + q*4 + r)*FCH + cc];
    }
  }
  #pragma unroll
  for (int jj = 0; jj < 8; ++jj) {
    const int nt = w + 4*jj;
    const bool isR = (jj < 4);
    const int cc = (isR ? nt*16 : (nt-16)*16) + i15;
    const float bias = isR ? br[cc] : bs[cc];
    #pragma unroll
    for (int mt = 0; mt < 2; ++mt)
      #pragma unroll
      for (int r = 0; r < 4; ++r) {
        const int g2 = rb + mt*16 + q*4 + r;
        float vv = acc[jj][mt][r] + bias;
        if (isR) vv += bf2f(resv[jj][mt][r]);
        else if (!first) vv += bf2f(skv[jj-4][mt][r]);
        u16 hv = f2bf(vv);
        if (isR) outBf[(size_t)g2*FCH + cc] = hv;
        else     skipB[(size_t)g2*FCH + cc] = hv;
      }
  }
}

// ---------------------------------------------------------------------------
// Final head: h=selu(skip); h=selu(h@Wd1+bd1); out=h@Wd2+bd2  -- OUT IS FP32
// ---------------------------------------------------------------------------
__global__ __launch_bounds__(256, 2) void final_kernel(
    const u16* __restrict__ skipB, const u16* __restrict__ BpD1, const u16* __restrict__ BpD2,
    const float* __restrict__ bd1, const float* __restrict__ bd2, float* __restrict__ outp,
    int nT8)
{
  __shared__ __align__(16) u16 ldsH[64*264];
  __shared__ __align__(16) u16 ldsH2[64*72];
  const int tid = threadIdx.x;
  const int w = tid >> 6, lane = tid & 63, q = lane >> 4, i15 = lane & 15;
  const int rb = xcd_tile(blockIdx.x, nT8) * 64;
  const int sm = tid >> 2, sseg = tid & 3;

  {
    const u16* sp = skipB + (size_t)(rb + sm)*256 + sseg*64;
    u16* dr = &ldsH[sm*264 + sseg*64];
    #pragma unroll
    for (int u = 0; u < 8; ++u) {
      uint4 raw = *reinterpret_cast<const uint4*>(sp + u*8);
      u32 rr[4] = {raw.x, raw.y, raw.z, raw.w};
      uint4 o;
      u32 oo[4];
      #pragma unroll
      for (int p = 0; p < 4; ++p) {
        float e0 = seluf(bf2f((u16)(rr[p] & 0xffffu)));
        float e1 = seluf(bf2f((u16)(rr[p] >> 16)));
        oo[p] = (u32)f2bf(e0) | ((u32)f2bf(e1) << 16);
      }
      o.x = oo[0]; o.y = oo[1]; o.z = oo[2]; o.w = oo[3];
      *reinterpret_cast<uint4*>(dr + u*8) = o;
    }
  }
  __syncthreads();

  f4v a1[4];
  #pragma unroll
  for (int mt = 0; mt < 4; ++mt) a1[mt] = (f4v){0.f,0.f,0.f,0.f};
  for (int kc = 0; kc < 8; ++kc) {
    s8v b = *reinterpret_cast<const s8v*>(BpD1 + ((size_t)(kc*4 + w)*64 + lane)*8);
    #pragma unroll
    for (int mt = 0; mt < 4; ++mt) {
      s8v af = *reinterpret_cast<const s8v*>(&ldsH[(mt*16 + i15)*264 + kc*32 + q*8]);
      a1[mt] = __builtin_amdgcn_mfma_f32_16x16x32_bf16(af, b, a1[mt], 0,0,0);
    }
  }
  const float bb1 = bd1[w*16 + i15];
  #pragma unroll
  for (int mt = 0; mt < 4; ++mt)
    #pragma unroll
    for (int r = 0; r < 4; ++r)
      ldsH2[(mt*16 + q*4 + r)*72 + w*16 + i15] = f2bf(seluf(a1[mt][r] + bb1));
  __syncthreads();

  f4v a2[4];
  #pragma unroll
  for (int mt = 0; mt < 4; ++mt) a2[mt] = (f4v){0.f,0.f,0.f,0.f};
  #pragma unroll
  for (int kc = 0; kc < 2; ++kc) {
    s8v b = *reinterpret_cast<const s8v*>(BpD2 + ((size_t)(kc*4 + w)*64 + lane)*8);
    #pragma unroll
    for (int mt = 0; mt < 4; ++mt) {
      s8v af = *reinterpret_cast<const s8v*>(&ldsH2[(mt*16 + i15)*72 + kc*32 + q*8]);
      a2[mt] = __builtin_amdgcn_mfma_f32_16x16x32_bf16(af, b, a2[mt], 0,0,0);
    }
  }
  const float bb2 = bd2[w*16 + i15];
  #pragma unroll
  for (int mt = 0; mt < 4; ++mt)
    #pragma unroll
    for (int r = 0; r < 4; ++r)
      outp[(size_t)(rb + mt*16 + q*4 + r)*64 + w*16 + i15] = a2[mt][r] + bb2;  // FP32
}

// Diagnostic sentinel (should never fire; ws proven >= 84 MB).
__global__ __launch_bounds__(256) void zero_kernel(uint4* __restrict__ outp, int n16)
{
  int i = blockIdx.x*256 + threadIdx.x;
  if (i < n16) outp[i] = (uint4){0u,0u,0u,0u};
}

// ---------------------------------------------------------------------------
extern "C" void kernel_launch(void* const* d_in, const int* in_sizes, int n_in,
                              void* d_out, int out_size, void* d_ws, size_t ws_size,
                              hipStream_t stream)
{
  (void)n_in;
  const float* x   = (const float*)d_in[0];
  const float* Wc  = (const float*)d_in[1];
  const float* Wf  = (const float*)d_in[2];
  const float* Wg  = (const float*)d_in[3];
  const float* Wr  = (const float*)d_in[4];
  const float* br  = (const float*)d_in[5];
  const float* Ws  = (const float*)d_in[6];
  const float* bs  = (const float*)d_in[7];
  const float* Wd1 = (const float*)d_in[8];
  const float* bd1 = (const float*)d_in[9];
  const float* Wd2 = (const float*)d_in[10];
  const float* bd2 = (const float*)d_in[11];

  const size_t ROWS = (size_t)in_sizes[0] / 64;     // B*T = 32768
  const int gridC = (int)(ROWS / 64);               // 512  (conv0 / final)
  const int gridL = (int)(ROWS / 32);               // 1024 (layers)
  const int nT8C = (gridC % 8 == 0) ? gridC / 8 : 0;
  const int nT8L = (gridL % 8 == 0) ? gridL / 8 : 0;

  const size_t packsB = (size_t)6248 * 512 * 2;     // 6.4 MB
  const size_t bfBuf  = ROWS * 256 * 2;             // 16.78 MB
  const size_t needB = packsB + 3*bfBuf;            // 56.7 MB

  if (ws_size < needB) {
    int n16 = (out_size * 4) / 16;                  // fp32 out
    zero_kernel<<<(n16 + 255)/256, 256, 0, stream>>>((uint4*)d_out, n16);
    return;
  }

  char* ws = (char*)d_ws;
  u16* Bp1    = (u16*)ws;            ws += (size_t)4096*512*2;
  u16* Bp2    = (u16*)ws;            ws += (size_t)2048*512*2;
  u16* Bp0    = (u16*)ws;            ws += (size_t)64*512*2;
  u16* BpD1   = (u16*)ws;            ws += (size_t)32*512*2;
  u16* BpD2   = (u16*)ws;            ws += (size_t)8*512*2;
  u16* skipB  = (u16*)ws;            ws += bfBuf;
  u16* bufA   = (u16*)ws;            ws += bfBuf;
  u16* bufB   = (u16*)ws;            ws += bfBuf;

  pack_kernel<<<1562, 256, 0, stream>>>(Wc, Wf, Wg, Wr, Ws, Wd1, Wd2,
                                        Bp1, Bp2, Bp0, BpD1, BpD2);
  conv0_kernel<<<gridC, 256, 0, stream>>>(x, bufA, Bp0, nT8C);
  u16* bufs[2] = {bufA, bufB};
  for (int i = 0; i < 8; ++i) {
    layer_kernel<<<gridL, 256, 0, stream>>>(
        bufs[i & 1], bufs[(i + 1) & 1], skipB,
        Bp1 + (size_t)i*262144, Bp2 + (size_t)i*131072,
        br + i*256, bs + i*256, 2 << i, (i == 0) ? 1 : 0, nT8L);
  }
  final_kernel<<<gridC, 256, 0, stream>>>(skipB, BpD1, BpD2, bd1, bd2,
                                          (float*)d_out, nT8C);
}

// Round 9
// 487.004 us; speedup vs baseline: 1.2276x; 1.0100x over previous
//
#include <hip/hip_runtime.h>
#include <cstdint>

typedef unsigned short u16;
typedef unsigned int u32;
typedef __attribute__((ext_vector_type(8))) short s8v;   // 8 bf16 (4 VGPRs)
typedef __attribute__((ext_vector_type(4))) float f4v;   // MFMA acc

#define FCH 256

__device__ __forceinline__ float bf2f(u16 u){ return __uint_as_float(((u32)u)<<16); }
__device__ __forceinline__ u16 f2bf(float x){
  u32 u = __float_as_uint(x);
  u += 0x7fffu + ((u>>16)&1u);
  return (u16)(u>>16);
}
// Fast reciprocal (v_rcp_f32, ~1e-5 rel err; bf16 outputs tolerate easily).
// Without -ffast-math, 1.f/x expands to ~10-op IEEE div sequence -- 2 divs x
// 64 elems was ~1200 VALU insts/wave on the serial stage1->stage2 path.
__device__ __forceinline__ float rcpf(float x){ return __builtin_amdgcn_rcpf(x); }
__device__ __forceinline__ uint4 pack8(float4 a, float4 b){
  uint4 o;
  o.x = (u32)f2bf(a.x) | ((u32)f2bf(a.y)<<16);
  o.y = (u32)f2bf(a.z) | ((u32)f2bf(a.w)<<16);
  o.z = (u32)f2bf(b.x) | ((u32)f2bf(b.y)<<16);
  o.w = (u32)f2bf(b.z) | ((u32)f2bf(b.w)<<16);
  return o;
}
__device__ __forceinline__ float seluf(float x){
  const float sc = 1.0507009873554805f, al = 1.6732632423543772f;
  return x > 0.f ? sc*x : sc*al*(__expf(x)-1.f);
}
// Masked 16B load: AND each dword with m (m=0 zeroes the fragment).
__device__ __forceinline__ s8v ldmask(const u16* p, u32 m){
  uint4 r = *reinterpret_cast<const uint4*>(p);
  r.x &= m; r.y &= m; r.z &= m; r.w &= m;
  s8v v; *reinterpret_cast<uint4*>(&v) = r;
  return v;
}
// XCD-stripe swizzle.
__device__ __forceinline__ int xcd_tile(int bid, int nT8){
  return nT8 ? ((bid & 7) * nT8 + (bid >> 3)) : bid;
}

// ---------------------------------------------------------------------------
// Weight packing (fp32 -> bf16 fragments): lane l slot j of frag (kc,nt) =
// B[kc*32 + (l>>4)*8 + j][nt*16 + (l&15)]  (16B/lane contiguous)
// ---------------------------------------------------------------------------
__global__ __launch_bounds__(256) void pack_kernel(
    const float* __restrict__ Wc, const float* __restrict__ Wf, const float* __restrict__ Wg,
    const float* __restrict__ Wr, const float* __restrict__ Ws,
    const float* __restrict__ Wd1, const float* __restrict__ Wd2,
    u16* __restrict__ Bp1, u16* __restrict__ Bp2, u16* __restrict__ Bp0,
    u16* __restrict__ BpD1, u16* __restrict__ BpD2)
{
  int gid = blockIdx.x*256 + threadIdx.x;
  int frag = gid >> 6;
  int lane = gid & 63;
  int q = lane >> 4, i15 = lane & 15;
  u16 v[8];
  u16* dst;
  if (frag < 4096) {                       // Bp1: [Wf|Wg] K=512 (tap-major)
    int layer = frag >> 9, rem = frag & 511;
    int kc = rem >> 5, nt = rem & 31;
    int n = nt*16 + i15;
    const float* W = (n < 256) ? Wf : Wg;
    int nn = (n < 256) ? n : n - 256;
    #pragma unroll
    for (int j = 0; j < 8; ++j) {
      int k = kc*32 + q*8 + j;
      int tap = k >> 8, cin = k & 255;
      v[j] = f2bf(W[((size_t)((layer*2 + tap)*256 + cin))*256 + nn]);
    }
    dst = Bp1 + (size_t)frag*512 + lane*8;
  } else if (frag < 6144) {                // Bp2: [Wr|Ws] K=256
    int f = frag - 4096;
    int layer = f >> 8, rem = f & 255;
    int kc = rem >> 5, nt = rem & 31;
    int n = nt*16 + i15;
    const float* W = (n < 256) ? Wr : Ws;
    int nn = (n < 256) ? n : n - 256;
    #pragma unroll
    for (int j = 0; j < 8; ++j) {
      int k = kc*32 + q*8 + j;
      v[j] = f2bf(W[((size_t)(layer*256 + k))*256 + nn]);
    }
    dst = Bp2 + (size_t)f*512 + lane*8;
  } else if (frag < 6208) {                // Bp0: Wc K=128
    int f = frag - 6144;
    int kc = f >> 4, nt = f & 15;
    int n = nt*16 + i15;
    #pragma unroll
    for (int j = 0; j < 8; ++j) {
      int k = kc*32 + q*8 + j;
      int tap = k >> 6, cin = k & 63;
      v[j] = f2bf(Wc[(size_t)(tap*64 + cin)*256 + n]);
    }
    dst = Bp0 + (size_t)f*512 + lane*8;
  } else if (frag < 6240) {                // BpD1: Wd1 [256,64]
    int f = frag - 6208;
    int kc = f >> 2, nt = f & 3;
    int n = nt*16 + i15;
    #pragma unroll
    for (int j = 0; j < 8; ++j) {
      int k = kc*32 + q*8 + j;
      v[j] = f2bf(Wd1[(size_t)k*64 + n]);
    }
    dst = BpD1 + (size_t)f*512 + lane*8;
  } else if (frag < 6248) {                // BpD2: Wd2 [64,64]
    int f = frag - 6240;
    int kc = f >> 2, nt = f & 3;
    int n = nt*16 + i15;
    #pragma unroll
    for (int j = 0; j < 8; ++j) {
      int k = kc*32 + q*8 + j;
      v[j] = f2bf(Wd2[(size_t)k*64 + n]);
    }
    dst = BpD2 + (size_t)f*512 + lane*8;
  } else return;
  uint4 o;
  o.x = (u32)v[0] | ((u32)v[1] << 16);
  o.y = (u32)v[2] | ((u32)v[3] << 16);
  o.z = (u32)v[4] | ((u32)v[5] << 16);
  o.w = (u32)v[6] | ((u32)v[7] << 16);
  *reinterpret_cast<uint4*>(dst) = o;
}

// ---------------------------------------------------------------------------
// Initial causal conv (dilation 1, no bias): out0 = [x[t-1]|x[t]] @ cat(Wc)
// ---------------------------------------------------------------------------
__global__ __launch_bounds__(256, 2) void conv0_kernel(
    const float* __restrict__ x, u16* __restrict__ outBf,
    const u16* __restrict__ Bp0, int nT8)
{
  __shared__ __align__(16) u16 ldsA[2][2048];
  const int tid = threadIdx.x;
  const int w = tid >> 6, lane = tid & 63, q = lane >> 4, i15 = lane & 15;
  const int rb = xcd_tile(blockIdx.x, nT8) * 64;
  const int sm = tid >> 2, sg = tid & 3;
  const int grow = rb + sm;
  const int tpos = grow & 4095;
  const int sunit = ((sm >> 4)*64 + sg*16 + ((sm & 15) ^ (sg << 1))) * 8;
  const int runit = (q*16 + (i15 ^ (q << 1))) * 8;

  f4v acc[4][4];
  #pragma unroll
  for (int jj = 0; jj < 4; ++jj)
    #pragma unroll
    for (int mt = 0; mt < 4; ++mt)
      acc[jj][mt] = (f4v){0.f,0.f,0.f,0.f};

  float4 f0 = {0.f,0.f,0.f,0.f}, f1 = {0.f,0.f,0.f,0.f};
  if (tpos >= 1) {
    const float* px = x + (size_t)(grow-1)*64 + sg*8;
    f0 = *reinterpret_cast<const float4*>(px);
    f1 = *reinterpret_cast<const float4*>(px + 4);
  }
  *reinterpret_cast<uint4*>(&ldsA[0][sunit]) = pack8(f0, f1);
  s8v bcur[4], bnxt[4];
  #pragma unroll
  for (int jj = 0; jj < 4; ++jj)
    bcur[jj] = *reinterpret_cast<const s8v*>(Bp0 + ((size_t)(w + 4*jj)*64 + lane)*8);
  __syncthreads();

  for (int kc = 0; kc < 4; ++kc) {
    const int cur = kc & 1;
    uint4 an = {0u,0u,0u,0u};
    if (kc < 3) {
      int kg = (kc+1)*32 + sg*8;
      int tap = kg >> 6, col = kg & 63;
      float4 g0 = {0.f,0.f,0.f,0.f}, g1 = {0.f,0.f,0.f,0.f};
      if (tap) {
        const float* px = x + (size_t)grow*64 + col;
        g0 = *reinterpret_cast<const float4*>(px);
        g1 = *reinterpret_cast<const float4*>(px + 4);
      } else if (tpos >= 1) {
        const float* px = x + (size_t)(grow-1)*64 + col;
        g0 = *reinterpret_cast<const float4*>(px);
        g1 = *reinterpret_cast<const float4*>(px + 4);
      }
      an = pack8(g0, g1);
      #pragma unroll
      for (int jj = 0; jj < 4; ++jj)
        bnxt[jj] = *reinterpret_cast<const s8v*>(Bp0 + (((size_t)(kc+1)*16 + (w + 4*jj))*64 + lane)*8);
    }
    s8v af[4];
    #pragma unroll
    for (int mt = 0; mt < 4; ++mt)
      af[mt] = *reinterpret_cast<const s8v*>(&ldsA[cur][mt*512 + runit]);
    #pragma unroll
    for (int jj = 0; jj < 4; ++jj)
      #pragma unroll
      for (int mt = 0; mt < 4; ++mt)
        acc[jj][mt] = __builtin_amdgcn_mfma_f32_16x16x32_bf16(af[mt], bcur[jj], acc[jj][mt], 0,0,0);
    if (kc < 3) {
      *reinterpret_cast<uint4*>(&ldsA[cur ^ 1][sunit]) = an;
      #pragma unroll
      for (int jj = 0; jj < 4; ++jj) bcur[jj] = bnxt[jj];
    }
    __syncthreads();
  }

  #pragma unroll
  for (int jj = 0; jj < 4; ++jj) {
    const int cc = (w + 4*jj)*16 + i15;
    #pragma unroll
    for (int mt = 0; mt < 4; ++mt)
      #pragma unroll
      for (int r = 0; r < 4; ++r) {
        const int g2 = rb + mt*16 + q*4 + r;
        outBf[(size_t)g2*FCH + cc] = f2bf(acc[jj][mt][r]);
      }
  }
}

// ---------------------------------------------------------------------------
// One WaveNet residual layer. R8 structure (M=32, 256 thr, 1024 blocks,
// half-chunk dist-2 pipeline, one barrier) with:
//  - v_rcp_f32 instead of IEEE divides in the activation (-~1200 VALU/wave)
//  - readfirstlane-hoisted wave index so weight/epilogue addresses are
//    SGPR-computable (saddr form; address adds move to the scalar pipe)
// ---------------------------------------------------------------------------
__global__ __launch_bounds__(256, 3) void layer_kernel(
    const u16* __restrict__ inBf, u16* __restrict__ outBf,
    u16* __restrict__ skipB,
    const u16* __restrict__ Bp1, const u16* __restrict__ Bp2,
    const float* __restrict__ br, const float* __restrict__ bs,
    int dil, int first, int nT8)
{
  __shared__ __align__(16) u16 ldsZ[32*264];     // 16.9 KB
  const int tid = threadIdx.x;
  const int w = __builtin_amdgcn_readfirstlane(tid >> 6);   // wave-uniform -> SGPR
  const int lane = tid & 63, q = lane >> 4, i15 = lane & 15;
  const int rb = xcd_tile(blockIdx.x, nT8) * 32;

  f4v acc[8][2];   // [jj: nt=w+4*jj][mt]
  #pragma unroll
  for (int jj = 0; jj < 8; ++jj)
    #pragma unroll
    for (int mt = 0; mt < 2; ++mt)
      acc[jj][mt] = (f4v){0.f,0.f,0.f,0.f};

  // ---------------- stage 1: half-chunk dist-2 pipeline ---------------------
  {
    const u16* a0p[2];   // tap0: row t-dil (safe addr; mask zeroes invalid)
    const u16* a1p[2];   // tap1: row t
    u32 am[2];
    #pragma unroll
    for (int mt = 0; mt < 2; ++mt) {
      const int row = rb + mt*16 + i15;
      const bool v = (row & 4095) >= dil;
      a0p[mt] = inBf + (size_t)(v ? row - dil : row)*FCH + q*8;
      a1p[mt] = inBf + (size_t)row*FCH + q*8;
      am[mt]  = v ? 0xffffffffu : 0u;
    }

    s8v bb[3][4], aa[2][2];
    // prologue: B for steps 0,1 (chunk 0, halves 0/1); A for chunk 0
    #pragma unroll
    for (int j2 = 0; j2 < 4; ++j2) {
      bb[0][j2] = *reinterpret_cast<const s8v*>(Bp1 + ((size_t)(w + 4*j2)*64 + lane)*8);
      bb[1][j2] = *reinterpret_cast<const s8v*>(Bp1 + ((size_t)(w + 16 + 4*j2)*64 + lane)*8);
    }
    #pragma unroll
    for (int mt = 0; mt < 2; ++mt)
      aa[0][mt] = ldmask(a0p[mt], am[mt]);

    #pragma unroll
    for (int s = 0; s < 32; ++s) {
      const int kc = s >> 1, h = s & 1;
      if (s + 2 < 32) {
        const int sp = s + 2, kcp = sp >> 1, hp = sp & 1;
        #pragma unroll
        for (int j2 = 0; j2 < 4; ++j2)
          bb[sp % 3][j2] = *reinterpret_cast<const s8v*>(
              Bp1 + (((size_t)kcp*32 + (w + 16*hp + 4*j2))*64 + lane)*8);
        if (hp == 0) {   // step sp starts chunk kcp: issue its A (2 steps early)
          if (kcp < 8) {
            #pragma unroll
            for (int mt = 0; mt < 2; ++mt)
              aa[kcp & 1][mt] = ldmask(a0p[mt] + kcp*32, am[mt]);
          } else {
            #pragma unroll
            for (int mt = 0; mt < 2; ++mt)
              aa[kcp & 1][mt] = *reinterpret_cast<const s8v*>(a1p[mt] + (kcp - 8)*32);
          }
        }
      }
      __builtin_amdgcn_s_setprio(1);
      #pragma unroll
      for (int j2 = 0; j2 < 4; ++j2)
        #pragma unroll
        for (int mt = 0; mt < 2; ++mt)
          acc[h*4 + j2][mt] = __builtin_amdgcn_mfma_f32_16x16x32_bf16(
              aa[kc & 1][mt], bb[s % 3][j2], acc[h*4 + j2][mt], 0,0,0);
      __builtin_amdgcn_s_setprio(0);
    }
  }

  // -------- issue stage-2 steps 0,1 B loads now (latency hides under exp) ---
  s8v s2b[3][4];
  #pragma unroll
  for (int j2 = 0; j2 < 4; ++j2) {
    s2b[0][j2] = *reinterpret_cast<const s8v*>(Bp2 + ((size_t)(w + 4*j2)*64 + lane)*8);
    s2b[1][j2] = *reinterpret_cast<const s8v*>(Bp2 + ((size_t)(w + 16 + 4*j2)*64 + lane)*8);
  }

  // ---------------- activation: Z -> LDS (C-layout -> row-major) ------------
  #pragma unroll
  for (int jj = 0; jj < 4; ++jj) {
    const int colb = (w + 4*jj)*16 + i15;
    #pragma unroll
    for (int mt = 0; mt < 2; ++mt)
      #pragma unroll
      for (int r = 0; r < 4; ++r) {
        float f = acc[jj][mt][r];
        float g = acc[jj+4][mt][r];
        float z = (1.f - 2.f*rcpf(__expf(2.f*f) + 1.f)) * rcpf(1.f + __expf(-g));
        ldsZ[(mt*16 + q*4 + r)*264 + colb] = f2bf(z);
      }
  }
  // zero acc for stage 2 (residual/skip/bias added in epilogue, f32)
  #pragma unroll
  for (int jj = 0; jj < 8; ++jj)
    #pragma unroll
    for (int mt = 0; mt < 2; ++mt)
      acc[jj][mt] = (f4v){0.f,0.f,0.f,0.f};
  __syncthreads();   // the ONLY barrier in this kernel

  // ---------------- stage 2: half-chunk dist-2 (B global, A LDS) ------------
  {
    s8v zf[2][2];
    #pragma unroll
    for (int mt = 0; mt < 2; ++mt)
      zf[0][mt] = *reinterpret_cast<const s8v*>(&ldsZ[(mt*16 + i15)*264 + q*8]);
    #pragma unroll
    for (int s = 0; s < 16; ++s) {
      const int kc = s >> 1, h = s & 1;
      if (s + 2 < 16) {
        const int sp = s + 2, kcp = sp >> 1, hp = sp & 1;
        #pragma unroll
        for (int j2 = 0; j2 < 4; ++j2)
          s2b[sp % 3][j2] = *reinterpret_cast<const s8v*>(
              Bp2 + (((size_t)kcp*32 + (w + 16*hp + 4*j2))*64 + lane)*8);
        if (hp == 0) {
          #pragma unroll
          for (int mt = 0; mt < 2; ++mt)
            zf[kcp & 1][mt] = *reinterpret_cast<const s8v*>(&ldsZ[(mt*16 + i15)*264 + kcp*32 + q*8]);
        }
      }
      __builtin_amdgcn_s_setprio(1);
      #pragma unroll
      for (int j2 = 0; j2 < 4; ++j2)
        #pragma unroll
        for (int mt = 0; mt < 2; ++mt)
          acc[h*4 + j2][mt] = __builtin_amdgcn_mfma_f32_16x16x32_bf16(
              zf[kc & 1][mt], s2b[s % 3][j2], acc[h*4 + j2][mt], 0,0,0);
      __builtin_amdgcn_s_setprio(0);
    }
  }

  // ---------------- epilogue: load residual/skip, add bias in f32, store ----
  u16 resv[4][2][4], skv[4][2][4];
  #pragma unroll
  for (int jj = 0; jj < 4; ++jj) {
    const int cc = (w + 4*jj)*16 + i15;
    #pragma unroll
    for (int mt = 0; mt < 2; ++mt)
      #pragma unroll
      for (int r = 0; r < 4; ++r)
        resv[jj][mt][r] = inBf[(size_t)(rb + mt*16 + q*4 + r)*FCH + cc];
  }
  if (!first) {
    #pragma unroll
    for (int jj = 0; jj < 4; ++jj) {
      const int cc = (w + 4*jj)*16 + i15;
      #pragma unroll
      for (int mt = 0; mt < 2; ++mt)
        #pragma unroll
        for (int r = 0; r < 4; ++r)
          skv[jj][mt][r] = skipB[(size_t)(rb + mt*16 + q*4 + r)*FCH + cc];
    }
  }
  #pragma unroll
  for (int jj = 0; jj < 8; ++jj) {
    const int nt = w + 4*jj;
    const bool isR = (jj < 4);
    const int cc = (isR ? nt*16 : (nt-16)*16) + i15;
    const float bias = isR ? br[cc] : bs[cc];
    #pragma unroll
    for (int mt = 0; mt < 2; ++mt)
      #pragma unroll
      for (int r = 0; r < 4; ++r) {
        const int g2 = rb + mt*16 + q*4 + r;
        float vv = acc[jj][mt][r] + bias;
        if (isR) vv += bf2f(resv[jj][mt][r]);
        else if (!first) vv += bf2f(skv[jj-4][mt][r]);
        u16 hv = f2bf(vv);
        if (isR) outBf[(size_t)g2*FCH + cc] = hv;
        else     skipB[(size_t)g2*FCH + cc] = hv;
      }
  }
}

// ---------------------------------------------------------------------------
// Final head: h=selu(skip); h=selu(h@Wd1+bd1); out=h@Wd2+bd2  -- OUT IS FP32
// ---------------------------------------------------------------------------
__global__ __launch_bounds__(256, 2) void final_kernel(
    const u16* __restrict__ skipB, const u16* __restrict__ BpD1, const u16* __restrict__ BpD2,
    const float* __restrict__ bd1, const float* __restrict__ bd2, float* __restrict__ outp,
    int nT8)
{
  __shared__ __align__(16) u16 ldsH[64*264];
  __shared__ __align__(16) u16 ldsH2[64*72];
  const int tid = threadIdx.x;
  const int w = tid >> 6, lane = tid & 63, q = lane >> 4, i15 = lane & 15;
  const int rb = xcd_tile(blockIdx.x, nT8) * 64;
  const int sm = tid >> 2, sseg = tid & 3;

  {
    const u16* sp = skipB + (size_t)(rb + sm)*256 + sseg*64;
    u16* dr = &ldsH[sm*264 + sseg*64];
    #pragma unroll
    for (int u = 0; u < 8; ++u) {
      uint4 raw = *reinterpret_cast<const uint4*>(sp + u*8);
      u32 rr[4] = {raw.x, raw.y, raw.z, raw.w};
      uint4 o;
      u32 oo[4];
      #pragma unroll
      for (int p = 0; p < 4; ++p) {
        float e0 = seluf(bf2f((u16)(rr[p] & 0xffffu)));
        float e1 = seluf(bf2f((u16)(rr[p] >> 16)));
        oo[p] = (u32)f2bf(e0) | ((u32)f2bf(e1) << 16);
      }
      o.x = oo[0]; o.y = oo[1]; o.z = oo[2]; o.w = oo[3];
      *reinterpret_cast<uint4*>(dr + u*8) = o;
    }
  }
  __syncthreads();

  f4v a1[4];
  #pragma unroll
  for (int mt = 0; mt < 4; ++mt) a1[mt] = (f4v){0.f,0.f,0.f,0.f};
  for (int kc = 0; kc < 8; ++kc) {
    s8v b = *reinterpret_cast<const s8v*>(BpD1 + ((size_t)(kc*4 + w)*64 + lane)*8);
    #pragma unroll
    for (int mt = 0; mt < 4; ++mt) {
      s8v af = *reinterpret_cast<const s8v*>(&ldsH[(mt*16 + i15)*264 + kc*32 + q*8]);
      a1[mt] = __builtin_amdgcn_mfma_f32_16x16x32_bf16(af, b, a1[mt], 0,0,0);
    }
  }
  const float bb1 = bd1[w*16 + i15];
  #pragma unroll
  for (int mt = 0; mt < 4; ++mt)
    #pragma unroll
    for (int r = 0; r < 4; ++r)
      ldsH2[(mt*16 + q*4 + r)*72 + w*16 + i15] = f2bf(seluf(a1[mt][r] + bb1));
  __syncthreads();

  f4v a2[4];
  #pragma unroll
  for (int mt = 0; mt < 4; ++mt) a2[mt] = (f4v){0.f,0.f,0.f,0.f};
  #pragma unroll
  for (int kc = 0; kc < 2; ++kc) {
    s8v b = *reinterpret_cast<const s8v*>(BpD2 + ((size_t)(kc*4 + w)*64 + lane)*8);
    #pragma unroll
    for (int mt = 0; mt < 4; ++mt) {
      s8v af = *reinterpret_cast<const s8v*>(&ldsH2[(mt*16 + i15)*72 + kc*32 + q*8]);
      a2[mt] = __builtin_amdgcn_mfma_f32_16x16x32_bf16(af, b, a2[mt], 0,0,0);
    }
  }
  const float bb2 = bd2[w*16 + i15];
  #pragma unroll
  for (int mt = 0; mt < 4; ++mt)
    #pragma unroll
    for (int r = 0; r < 4; ++r)
      outp[(size_t)(rb + mt*16 + q*4 + r)*64 + w*16 + i15] = a2[mt][r] + bb2;  // FP32
}

// Diagnostic sentinel (should never fire; ws proven >= 84 MB).
__global__ __launch_bounds__(256) void zero_kernel(uint4* __restrict__ outp, int n16)
{
  int i = blockIdx.x*256 + threadIdx.x;
  if (i < n16) outp[i] = (uint4){0u,0u,0u,0u};
}

// ---------------------------------------------------------------------------
extern "C" void kernel_launch(void* const* d_in, const int* in_sizes, int n_in,
                              void* d_out, int out_size, void* d_ws, size_t ws_size,
                              hipStream_t stream)
{
  (void)n_in;
  const float* x   = (const float*)d_in[0];
  const float* Wc  = (const float*)d_in[1];
  const float* Wf  = (const float*)d_in[2];
  const float* Wg  = (const float*)d_in[3];
  const float* Wr  = (const float*)d_in[4];
  const float* br  = (const float*)d_in[5];
  const float* Ws  = (const float*)d_in[6];
  const float* bs  = (const float*)d_in[7];
  const float* Wd1 = (const float*)d_in[8];
  const float* bd1 = (const float*)d_in[9];
  const float* Wd2 = (const float*)d_in[10];
  const float* bd2 = (const float*)d_in[11];

  const size_t ROWS = (size_t)in_sizes[0] / 64;     // B*T = 32768
  const int gridC = (int)(ROWS / 64);               // 512  (conv0 / final)
  const int gridL = (int)(ROWS / 32);               // 1024 (layers)
  const int nT8C = (gridC % 8 == 0) ? gridC / 8 : 0;
  const int nT8L = (gridL % 8 == 0) ? gridL / 8 : 0;

  const size_t packsB = (size_t)6248 * 512 * 2;     // 6.4 MB
  const size_t bfBuf  = ROWS * 256 * 2;             // 16.78 MB
  const size_t needB = packsB + 3*bfBuf;            // 56.7 MB

  if (ws_size < needB) {
    int n16 = (out_size * 4) / 16;                  // fp32 out
    zero_kernel<<<(n16 + 255)/256, 256, 0, stream>>>((uint4*)d_out, n16);
    return;
  }

  char* ws = (char*)d_ws;
  u16* Bp1    = (u16*)ws;            ws += (size_t)4096*512*2;
  u16* Bp2    = (u16*)ws;            ws += (size_t)2048*512*2;
  u16* Bp0    = (u16*)ws;            ws += (size_t)64*512*2;
  u16* BpD1   = (u16*)ws;            ws += (size_t)32*512*2;
  u16* BpD2   = (u16*)ws;            ws += (size_t)8*512*2;
  u16* skipB  = (u16*)ws;            ws += bfBuf;
  u16* bufA   = (u16*)ws;            ws += bfBuf;
  u16* bufB   = (u16*)ws;            ws += bfBuf;

  pack_kernel<<<1562, 256, 0, stream>>>(Wc, Wf, Wg, Wr, Ws, Wd1, Wd2,
                                        Bp1, Bp2, Bp0, BpD1, BpD2);
  conv0_kernel<<<gridC, 256, 0, stream>>>(x, bufA, Bp0, nT8C);
  u16* bufs[2] = {bufA, bufB};
  for (int i = 0; i < 8; ++i) {
    layer_kernel<<<gridL, 256, 0, stream>>>(
        bufs[i & 1], bufs[(i + 1) & 1], skipB,
        Bp1 + (size_t)i*262144, Bp2 + (size_t)i*131072,
        br + i*256, bs + i*256, 2 << i, (i == 0) ? 1 : 0, nT8L);
  }
  final_kernel<<<gridC, 256, 0, stream>>>(skipB, BpD1, BpD2, bd1, bd2,
                                          (float*)d_out, nT8C);
}

// Round 10
// 483.804 us; speedup vs baseline: 1.2357x; 1.0066x over previous
//
#include <hip/hip_runtime.h>
#include <cstdint>

typedef unsigned short u16;
typedef unsigned int u32;
typedef __attribute__((ext_vector_type(8))) short s8v;   // 8 bf16 (4 VGPRs)
typedef __attribute__((ext_vector_type(4))) float f4v;   // MFMA acc

#define FCH 256

__device__ __forceinline__ float bf2f(u16 u){ return __uint_as_float(((u32)u)<<16); }
__device__ __forceinline__ u16 f2bf(float x){
  u32 u = __float_as_uint(x);
  u += 0x7fffu + ((u>>16)&1u);
  return (u16)(u>>16);
}
// Fast reciprocal (v_rcp_f32, ~1e-5 rel err; bf16 outputs tolerate easily).
__device__ __forceinline__ float rcpf(float x){ return __builtin_amdgcn_rcpf(x); }
__device__ __forceinline__ uint4 pack8(float4 a, float4 b){
  uint4 o;
  o.x = (u32)f2bf(a.x) | ((u32)f2bf(a.y)<<16);
  o.y = (u32)f2bf(a.z) | ((u32)f2bf(a.w)<<16);
  o.z = (u32)f2bf(b.x) | ((u32)f2bf(b.y)<<16);
  o.w = (u32)f2bf(b.z) | ((u32)f2bf(b.w)<<16);
  return o;
}
__device__ __forceinline__ float seluf(float x){
  const float sc = 1.0507009873554805f, al = 1.6732632423543772f;
  return x > 0.f ? sc*x : sc*al*(__expf(x)-1.f);
}
// Masked 16B load: AND each dword with m (m=0 zeroes the fragment).
__device__ __forceinline__ s8v ldmask(const u16* p, u32 m){
  uint4 r = *reinterpret_cast<const uint4*>(p);
  r.x &= m; r.y &= m; r.z &= m; r.w &= m;
  s8v v; *reinterpret_cast<uint4*>(&v) = r;
  return v;
}
// XCD-stripe swizzle.
__device__ __forceinline__ int xcd_tile(int bid, int nT8){
  return nT8 ? ((bid & 7) * nT8 + (bid >> 3)) : bid;
}

// ---------------------------------------------------------------------------
// Weight packing (fp32 -> bf16 fragments): lane l slot j of frag (kc,nt) =
// B[kc*32 + (l>>4)*8 + j][nt*16 + (l&15)]  (16B/lane contiguous)
// ---------------------------------------------------------------------------
__global__ __launch_bounds__(256) void pack_kernel(
    const float* __restrict__ Wc, const float* __restrict__ Wf, const float* __restrict__ Wg,
    const float* __restrict__ Wr, const float* __restrict__ Ws,
    const float* __restrict__ Wd1, const float* __restrict__ Wd2,
    u16* __restrict__ Bp1, u16* __restrict__ Bp2, u16* __restrict__ Bp0,
    u16* __restrict__ BpD1, u16* __restrict__ BpD2)
{
  int gid = blockIdx.x*256 + threadIdx.x;
  int frag = gid >> 6;
  int lane = gid & 63;
  int q = lane >> 4, i15 = lane & 15;
  u16 v[8];
  u16* dst;
  if (frag < 4096) {                       // Bp1: [Wf|Wg] K=512 (tap-major)
    int layer = frag >> 9, rem = frag & 511;
    int kc = rem >> 5, nt = rem & 31;
    int n = nt*16 + i15;
    const float* W = (n < 256) ? Wf : Wg;
    int nn = (n < 256) ? n : n - 256;
    #pragma unroll
    for (int j = 0; j < 8; ++j) {
      int k = kc*32 + q*8 + j;
      int tap = k >> 8, cin = k & 255;
      v[j] = f2bf(W[((size_t)((layer*2 + tap)*256 + cin))*256 + nn]);
    }
    dst = Bp1 + (size_t)frag*512 + lane*8;
  } else if (frag < 6144) {                // Bp2: [Wr|Ws] K=256
    int f = frag - 4096;
    int layer = f >> 8, rem = f & 255;
    int kc = rem >> 5, nt = rem & 31;
    int n = nt*16 + i15;
    const float* W = (n < 256) ? Wr : Ws;
    int nn = (n < 256) ? n : n - 256;
    #pragma unroll
    for (int j = 0; j < 8; ++j) {
      int k = kc*32 + q*8 + j;
      v[j] = f2bf(W[((size_t)(layer*256 + k))*256 + nn]);
    }
    dst = Bp2 + (size_t)f*512 + lane*8;
  } else if (frag < 6208) {                // Bp0: Wc K=128
    int f = frag - 6144;
    int kc = f >> 4, nt = f & 15;
    int n = nt*16 + i15;
    #pragma unroll
    for (int j = 0; j < 8; ++j) {
      int k = kc*32 + q*8 + j;
      int tap = k >> 6, cin = k & 63;
      v[j] = f2bf(Wc[(size_t)(tap*64 + cin)*256 + n]);
    }
    dst = Bp0 + (size_t)f*512 + lane*8;
  } else if (frag < 6240) {                // BpD1: Wd1 [256,64]
    int f = frag - 6208;
    int kc = f >> 2, nt = f & 3;
    int n = nt*16 + i15;
    #pragma unroll
    for (int j = 0; j < 8; ++j) {
      int k = kc*32 + q*8 + j;
      v[j] = f2bf(Wd1[(size_t)k*64 + n]);
    }
    dst = BpD1 + (size_t)f*512 + lane*8;
  } else if (frag < 6248) {                // BpD2: Wd2 [64,64]
    int f = frag - 6240;
    int kc = f >> 2, nt = f & 3;
    int n = nt*16 + i15;
    #pragma unroll
    for (int j = 0; j < 8; ++j) {
      int k = kc*32 + q*8 + j;
      v[j] = f2bf(Wd2[(size_t)k*64 + n]);
    }
    dst = BpD2 + (size_t)f*512 + lane*8;
  } else return;
  uint4 o;
  o.x = (u32)v[0] | ((u32)v[1] << 16);
  o.y = (u32)v[2] | ((u32)v[3] << 16);
  o.z = (u32)v[4] | ((u32)v[5] << 16);
  o.w = (u32)v[6] | ((u32)v[7] << 16);
  *reinterpret_cast<uint4*>(dst) = o;
}

// ---------------------------------------------------------------------------
// Initial causal conv (dilation 1, no bias): out0 = [x[t-1]|x[t]] @ cat(Wc)
// ---------------------------------------------------------------------------
__global__ __launch_bounds__(256, 2) void conv0_kernel(
    const float* __restrict__ x, u16* __restrict__ outBf,
    const u16* __restrict__ Bp0, int nT8)
{
  __shared__ __align__(16) u16 ldsA[2][2048];
  const int tid = threadIdx.x;
  const int w = tid >> 6, lane = tid & 63, q = lane >> 4, i15 = lane & 15;
  const int rb = xcd_tile(blockIdx.x, nT8) * 64;
  const int sm = tid >> 2, sg = tid & 3;
  const int grow = rb + sm;
  const int tpos = grow & 4095;
  const int sunit = ((sm >> 4)*64 + sg*16 + ((sm & 15) ^ (sg << 1))) * 8;
  const int runit = (q*16 + (i15 ^ (q << 1))) * 8;

  f4v acc[4][4];
  #pragma unroll
  for (int jj = 0; jj < 4; ++jj)
    #pragma unroll
    for (int mt = 0; mt < 4; ++mt)
      acc[jj][mt] = (f4v){0.f,0.f,0.f,0.f};

  float4 f0 = {0.f,0.f,0.f,0.f}, f1 = {0.f,0.f,0.f,0.f};
  if (tpos >= 1) {
    const float* px = x + (size_t)(grow-1)*64 + sg*8;
    f0 = *reinterpret_cast<const float4*>(px);
    f1 = *reinterpret_cast<const float4*>(px + 4);
  }
  *reinterpret_cast<uint4*>(&ldsA[0][sunit]) = pack8(f0, f1);
  s8v bcur[4], bnxt[4];
  #pragma unroll
  for (int jj = 0; jj < 4; ++jj)
    bcur[jj] = *reinterpret_cast<const s8v*>(Bp0 + ((size_t)(w + 4*jj)*64 + lane)*8);
  __syncthreads();

  for (int kc = 0; kc < 4; ++kc) {
    const int cur = kc & 1;
    uint4 an = {0u,0u,0u,0u};
    if (kc < 3) {
      int kg = (kc+1)*32 + sg*8;
      int tap = kg >> 6, col = kg & 63;
      float4 g0 = {0.f,0.f,0.f,0.f}, g1 = {0.f,0.f,0.f,0.f};
      if (tap) {
        const float* px = x + (size_t)grow*64 + col;
        g0 = *reinterpret_cast<const float4*>(px);
        g1 = *reinterpret_cast<const float4*>(px + 4);
      } else if (tpos >= 1) {
        const float* px = x + (size_t)(grow-1)*64 + col;
        g0 = *reinterpret_cast<const float4*>(px);
        g1 = *reinterpret_cast<const float4*>(px + 4);
      }
      an = pack8(g0, g1);
      #pragma unroll
      for (int jj = 0; jj < 4; ++jj)
        bnxt[jj] = *reinterpret_cast<const s8v*>(Bp0 + (((size_t)(kc+1)*16 + (w + 4*jj))*64 + lane)*8);
    }
    s8v af[4];
    #pragma unroll
    for (int mt = 0; mt < 4; ++mt)
      af[mt] = *reinterpret_cast<const s8v*>(&ldsA[cur][mt*512 + runit]);
    #pragma unroll
    for (int jj = 0; jj < 4; ++jj)
      #pragma unroll
      for (int mt = 0; mt < 4; ++mt)
        acc[jj][mt] = __builtin_amdgcn_mfma_f32_16x16x32_bf16(af[mt], bcur[jj], acc[jj][mt], 0,0,0);
    if (kc < 3) {
      *reinterpret_cast<uint4*>(&ldsA[cur ^ 1][sunit]) = an;
      #pragma unroll
      for (int jj = 0; jj < 4; ++jj) bcur[jj] = bnxt[jj];
    }
    __syncthreads();
  }

  #pragma unroll
  for (int jj = 0; jj < 4; ++jj) {
    const int cc = (w + 4*jj)*16 + i15;
    #pragma unroll
    for (int mt = 0; mt < 4; ++mt)
      #pragma unroll
      for (int r = 0; r < 4; ++r) {
        const int g2 = rb + mt*16 + q*4 + r;
        outBf[(size_t)g2*FCH + cc] = f2bf(acc[jj][mt][r]);
      }
  }
}

// ---------------------------------------------------------------------------
// One WaveNet residual layer. R9 structure (M=32, 256 thr, 1024 blocks,
// half-chunk pipeline, one barrier, rcpf activation, readfirstlane wave idx)
// with B prefetch deepened to DIST-3 half-chunk (bb[4][4]): cover 117+cy vs
// the ~78cy all prior variants had (R8 taught: dist-2-half == dist-1-full).
// ---------------------------------------------------------------------------
__global__ __launch_bounds__(256, 3) void layer_kernel(
    const u16* __restrict__ inBf, u16* __restrict__ outBf,
    u16* __restrict__ skipB,
    const u16* __restrict__ Bp1, const u16* __restrict__ Bp2,
    const float* __restrict__ br, const float* __restrict__ bs,
    int dil, int first, int nT8)
{
  __shared__ __align__(16) u16 ldsZ[32*264];     // 16.9 KB
  const int tid = threadIdx.x;
  const int w = __builtin_amdgcn_readfirstlane(tid >> 6);   // wave-uniform -> SGPR
  const int lane = tid & 63, q = lane >> 4, i15 = lane & 15;
  const int rb = xcd_tile(blockIdx.x, nT8) * 32;

  f4v acc[8][2];   // [jj: nt=w+4*jj][mt]
  #pragma unroll
  for (int jj = 0; jj < 8; ++jj)
    #pragma unroll
    for (int mt = 0; mt < 2; ++mt)
      acc[jj][mt] = (f4v){0.f,0.f,0.f,0.f};

  // ---------------- stage 1: half-chunk DIST-3 pipeline ---------------------
  {
    const u16* a0p[2];   // tap0: row t-dil (safe addr; mask zeroes invalid)
    const u16* a1p[2];   // tap1: row t
    u32 am[2];
    #pragma unroll
    for (int mt = 0; mt < 2; ++mt) {
      const int row = rb + mt*16 + i15;
      const bool v = (row & 4095) >= dil;
      a0p[mt] = inBf + (size_t)(v ? row - dil : row)*FCH + q*8;
      a1p[mt] = inBf + (size_t)row*FCH + q*8;
      am[mt]  = v ? 0xffffffffu : 0u;
    }

    s8v bb[4][4], aa[2][2];
    // prologue: B for steps 0,1,2 = frags (kc0,h0),(kc0,h1),(kc1,h0); A chunk 0
    #pragma unroll
    for (int j2 = 0; j2 < 4; ++j2) {
      bb[0][j2] = *reinterpret_cast<const s8v*>(Bp1 + ((size_t)(w + 4*j2)*64 + lane)*8);
      bb[1][j2] = *reinterpret_cast<const s8v*>(Bp1 + ((size_t)(w + 16 + 4*j2)*64 + lane)*8);
      bb[2][j2] = *reinterpret_cast<const s8v*>(Bp1 + ((size_t)(32 + w + 4*j2)*64 + lane)*8);
    }
    #pragma unroll
    for (int mt = 0; mt < 2; ++mt)
      aa[0][mt] = ldmask(a0p[mt], am[mt]);

    #pragma unroll
    for (int s = 0; s < 32; ++s) {
      const int kc = s >> 1, h = s & 1;
      if (s + 3 < 32) {                      // B: dist-3 half-chunk prefetch
        const int sp = s + 3, kcp = sp >> 1, hp = sp & 1;
        #pragma unroll
        for (int j2 = 0; j2 < 4; ++j2)
          bb[sp & 3][j2] = *reinterpret_cast<const s8v*>(
              Bp1 + (((size_t)kcp*32 + (w + 16*hp + 4*j2))*64 + lane)*8);
      }
      if (s + 2 < 32) {                      // A: 1-chunk (2-step) lead
        const int sa = s + 2, kca = sa >> 1, ha = sa & 1;
        if (ha == 0) {
          if (kca < 8) {
            #pragma unroll
            for (int mt = 0; mt < 2; ++mt)
              aa[kca & 1][mt] = ldmask(a0p[mt] + kca*32, am[mt]);
          } else {
            #pragma unroll
            for (int mt = 0; mt < 2; ++mt)
              aa[kca & 1][mt] = *reinterpret_cast<const s8v*>(a1p[mt] + (kca - 8)*32);
          }
        }
      }
      __builtin_amdgcn_s_setprio(1);
      #pragma unroll
      for (int j2 = 0; j2 < 4; ++j2)
        #pragma unroll
        for (int mt = 0; mt < 2; ++mt)
          acc[h*4 + j2][mt] = __builtin_amdgcn_mfma_f32_16x16x32_bf16(
              aa[kc & 1][mt], bb[s & 3][j2], acc[h*4 + j2][mt], 0,0,0);
      __builtin_amdgcn_s_setprio(0);
    }
  }

  // -------- issue stage-2 steps 0,1,2 B loads now (latency under exp) -------
  s8v s2b[4][4];
  #pragma unroll
  for (int j2 = 0; j2 < 4; ++j2) {
    s2b[0][j2] = *reinterpret_cast<const s8v*>(Bp2 + ((size_t)(w + 4*j2)*64 + lane)*8);
    s2b[1][j2] = *reinterpret_cast<const s8v*>(Bp2 + ((size_t)(w + 16 + 4*j2)*64 + lane)*8);
    s2b[2][j2] = *reinterpret_cast<const s8v*>(Bp2 + ((size_t)(32 + w + 4*j2)*64 + lane)*8);
  }

  // ---------------- activation: Z -> LDS (C-layout -> row-major) ------------
  #pragma unroll
  for (int jj = 0; jj < 4; ++jj) {
    const int colb = (w + 4*jj)*16 + i15;
    #pragma unroll
    for (int mt = 0; mt < 2; ++mt)
      #pragma unroll
      for (int r = 0; r < 4; ++r) {
        float f = acc[jj][mt][r];
        float g = acc[jj+4][mt][r];
        float z = (1.f - 2.f*rcpf(__expf(2.f*f) + 1.f)) * rcpf(1.f + __expf(-g));
        ldsZ[(mt*16 + q*4 + r)*264 + colb] = f2bf(z);
      }
  }
  // zero acc for stage 2 (residual/skip/bias added in epilogue, f32)
  #pragma unroll
  for (int jj = 0; jj < 8; ++jj)
    #pragma unroll
    for (int mt = 0; mt < 2; ++mt)
      acc[jj][mt] = (f4v){0.f,0.f,0.f,0.f};
  __syncthreads();   // the ONLY barrier in this kernel

  // ---------------- stage 2: half-chunk DIST-3 (B global, A LDS) ------------
  {
    s8v zf[2][2];
    #pragma unroll
    for (int mt = 0; mt < 2; ++mt)
      zf[0][mt] = *reinterpret_cast<const s8v*>(&ldsZ[(mt*16 + i15)*264 + q*8]);
    #pragma unroll
    for (int s = 0; s < 16; ++s) {
      const int kc = s >> 1, h = s & 1;
      if (s + 3 < 16) {
        const int sp = s + 3, kcp = sp >> 1, hp = sp & 1;
        #pragma unroll
        for (int j2 = 0; j2 < 4; ++j2)
          s2b[sp & 3][j2] = *reinterpret_cast<const s8v*>(
              Bp2 + (((size_t)kcp*32 + (w + 16*hp + 4*j2))*64 + lane)*8);
      }
      if (s + 2 < 16) {
        const int sa = s + 2, kca = sa >> 1, ha = sa & 1;
        if (ha == 0) {
          #pragma unroll
          for (int mt = 0; mt < 2; ++mt)
            zf[kca & 1][mt] = *reinterpret_cast<const s8v*>(&ldsZ[(mt*16 + i15)*264 + kca*32 + q*8]);
        }
      }
      __builtin_amdgcn_s_setprio(1);
      #pragma unroll
      for (int j2 = 0; j2 < 4; ++j2)
        #pragma unroll
        for (int mt = 0; mt < 2; ++mt)
          acc[h*4 + j2][mt] = __builtin_amdgcn_mfma_f32_16x16x32_bf16(
              zf[kc & 1][mt], s2b[s & 3][j2], acc[h*4 + j2][mt], 0,0,0);
      __builtin_amdgcn_s_setprio(0);
    }
  }

  // ---------------- epilogue: load residual/skip, add bias in f32, store ----
  u16 resv[4][2][4], skv[4][2][4];
  #pragma unroll
  for (int jj = 0; jj < 4; ++jj) {
    const int cc = (w + 4*jj)*16 + i15;
    #pragma unroll
    for (int mt = 0; mt < 2; ++mt)
      #pragma unroll
      for (int r = 0; r < 4; ++r)
        resv[jj][mt][r] = inBf[(size_t)(rb + mt*16 + q*4 + r)*FCH + cc];
  }
  if (!first) {
    #pragma unroll
    for (int jj = 0; jj < 4; ++jj) {
      const int cc = (w + 4*jj)*16 + i15;
      #pragma unroll
      for (int mt = 0; mt < 2; ++mt)
        #pragma unroll
        for (int r = 0; r < 4; ++r)
          skv[jj][mt][r] = skipB[(size_t)(rb + mt*16 + q*4 + r)*FCH + cc];
    }
  }
  #pragma unroll
  for (int jj = 0; jj < 8; ++jj) {
    const int nt = w + 4*jj;
    const bool isR = (jj < 4);
    const int cc = (isR ? nt*16 : (nt-16)*16) + i15;
    const float bias = isR ? br[cc] : bs[cc];
    #pragma unroll
    for (int mt = 0; mt < 2; ++mt)
      #pragma unroll
      for (int r = 0; r < 4; ++r) {
        const int g2 = rb + mt*16 + q*4 + r;
        float vv = acc[jj][mt][r] + bias;
        if (isR) vv += bf2f(resv[jj][mt][r]);
        else if (!first) vv += bf2f(skv[jj-4][mt][r]);
        u16 hv = f2bf(vv);
        if (isR) outBf[(size_t)g2*FCH + cc] = hv;
        else     skipB[(size_t)g2*FCH + cc] = hv;
      }
  }
}

// ---------------------------------------------------------------------------
// Final head: h=selu(skip); h=selu(h@Wd1+bd1); out=h@Wd2+bd2  -- OUT IS FP32
// ---------------------------------------------------------------------------
__global__ __launch_bounds__(256, 2) void final_kernel(
    const u16* __restrict__ skipB, const u16* __restrict__ BpD1, const u16* __restrict__ BpD2,
    const float* __restrict__ bd1, const float* __restrict__ bd2, float* __restrict__ outp,
    int nT8)
{
  __shared__ __align__(16) u16 ldsH[64*264];
  __shared__ __align__(16) u16 ldsH2[64*72];
  const int tid = threadIdx.x;
  const int w = tid >> 6, lane = tid & 63, q = lane >> 4, i15 = lane & 15;
  const int rb = xcd_tile(blockIdx.x, nT8) * 64;
  const int sm = tid >> 2, sseg = tid & 3;

  {
    const u16* sp = skipB + (size_t)(rb + sm)*256 + sseg*64;
    u16* dr = &ldsH[sm*264 + sseg*64];
    #pragma unroll
    for (int u = 0; u < 8; ++u) {
      uint4 raw = *reinterpret_cast<const uint4*>(sp + u*8);
      u32 rr[4] = {raw.x, raw.y, raw.z, raw.w};
      uint4 o;
      u32 oo[4];
      #pragma unroll
      for (int p = 0; p < 4; ++p) {
        float e0 = seluf(bf2f((u16)(rr[p] & 0xffffu)));
        float e1 = seluf(bf2f((u16)(rr[p] >> 16)));
        oo[p] = (u32)f2bf(e0) | ((u32)f2bf(e1) << 16);
      }
      o.x = oo[0]; o.y = oo[1]; o.z = oo[2]; o.w = oo[3];
      *reinterpret_cast<uint4*>(dr + u*8) = o;
    }
  }
  __syncthreads();

  f4v a1[4];
  #pragma unroll
  for (int mt = 0; mt < 4; ++mt) a1[mt] = (f4v){0.f,0.f,0.f,0.f};
  for (int kc = 0; kc < 8; ++kc) {
    s8v b = *reinterpret_cast<const s8v*>(BpD1 + ((size_t)(kc*4 + w)*64 + lane)*8);
    #pragma unroll
    for (int mt = 0; mt < 4; ++mt) {
      s8v af = *reinterpret_cast<const s8v*>(&ldsH[(mt*16 + i15)*264 + kc*32 + q*8]);
      a1[mt] = __builtin_amdgcn_mfma_f32_16x16x32_bf16(af, b, a1[mt], 0,0,0);
    }
  }
  const float bb1 = bd1[w*16 + i15];
  #pragma unroll
  for (int mt = 0; mt < 4; ++mt)
    #pragma unroll
    for (int r = 0; r < 4; ++r)
      ldsH2[(mt*16 + q*4 + r)*72 + w*16 + i15] = f2bf(seluf(a1[mt][r] + bb1));
  __syncthreads();

  f4v a2[4];
  #pragma unroll
  for (int mt = 0; mt < 4; ++mt) a2[mt] = (f4v){0.f,0.f,0.f,0.f};
  #pragma unroll
  for (int kc = 0; kc < 2; ++kc) {
    s8v b = *reinterpret_cast<const s8v*>(BpD2 + ((size_t)(kc*4 + w)*64 + lane)*8);
    #pragma unroll
    for (int mt = 0; mt < 4; ++mt) {
      s8v af = *reinterpret_cast<const s8v*>(&ldsH2[(mt*16 + i15)*72 + kc*32 + q*8]);
      a2[mt] = __builtin_amdgcn_mfma_f32_16x16x32_bf16(af, b, a2[mt], 0,0,0);
    }
  }
  const float bb2 = bd2[w*16 + i15];
  #pragma unroll
  for (int mt = 0; mt < 4; ++mt)
    #pragma unroll
    for (int r = 0; r < 4; ++r)
      outp[(size_t)(rb + mt*16 + q*4 + r)*64 + w*16 + i15] = a2[mt][r] + bb2;  // FP32
}

// Diagnostic sentinel (should never fire; ws proven >= 84 MB).
__global__ __launch_bounds__(256) void zero_kernel(uint4* __restrict__ outp, int n16)
{
  int i = blockIdx.x*256 + threadIdx.x;
  if (i < n16) outp[i] = (uint4){0u,0u,0u,0u};
}

// ---------------------------------------------------------------------------
extern "C" void kernel_launch(void* const* d_in, const int* in_sizes, int n_in,
                              void* d_out, int out_size, void* d_ws, size_t ws_size,
                              hipStream_t stream)
{
  (void)n_in;
  const float* x   = (const float*)d_in[0];
  const float* Wc  = (const float*)d_in[1];
  const float* Wf  = (const float*)d_in[2];
  const float* Wg  = (const float*)d_in[3];
  const float* Wr  = (const float*)d_in[4];
  const float* br  = (const float*)d_in[5];
  const float* Ws  = (const float*)d_in[6];
  const float* bs  = (const float*)d_in[7];
  const float* Wd1 = (const float*)d_in[8];
  const float* bd1 = (const float*)d_in[9];
  const float* Wd2 = (const float*)d_in[10];
  const float* bd2 = (const float*)d_in[11];

  const size_t ROWS = (size_t)in_sizes[0] / 64;     // B*T = 32768
  const int gridC = (int)(ROWS / 64);               // 512  (conv0 / final)
  const int gridL = (int)(ROWS / 32);               // 1024 (layers)
  const int nT8C = (gridC % 8 == 0) ? gridC / 8 : 0;
  const int nT8L = (gridL % 8 == 0) ? gridL / 8 : 0;

  const size_t packsB = (size_t)6248 * 512 * 2;     // 6.4 MB
  const size_t bfBuf  = ROWS * 256 * 2;             // 16.78 MB
  const size_t needB = packsB + 3*bfBuf;            // 56.7 MB

  if (ws_size < needB) {
    int n16 = (out_size * 4) / 16;                  // fp32 out
    zero_kernel<<<(n16 + 255)/256, 256, 0, stream>>>((uint4*)d_out, n16);
    return;
  }

  char* ws = (char*)d_ws;
  u16* Bp1    = (u16*)ws;            ws += (size_t)4096*512*2;
  u16* Bp2    = (u16*)ws;            ws += (size_t)2048*512*2;
  u16* Bp0    = (u16*)ws;            ws += (size_t)64*512*2;
  u16* BpD1   = (u16*)ws;            ws += (size_t)32*512*2;
  u16* BpD2   = (u16*)ws;            ws += (size_t)8*512*2;
  u16* skipB  = (u16*)ws;            ws += bfBuf;
  u16* bufA   = (u16*)ws;            ws += bfBuf;
  u16* bufB   = (u16*)ws;            ws += bfBuf;

  pack_kernel<<<1562, 256, 0, stream>>>(Wc, Wf, Wg, Wr, Ws, Wd1, Wd2,
                                        Bp1, Bp2, Bp0, BpD1, BpD2);
  conv0_kernel<<<gridC, 256, 0, stream>>>(x, bufA, Bp0, nT8C);
  u16* bufs[2] = {bufA, bufB};
  for (int i = 0; i < 8; ++i) {
    layer_kernel<<<gridL, 256, 0, stream>>>(
        bufs[i & 1], bufs[(i + 1) & 1], skipB,
        Bp1 + (size_t)i*262144, Bp2 + (size_t)i*131072,
        br + i*256, bs + i*256, 2 << i, (i == 0) ? 1 : 0, nT8L);
  }
  final_kernel<<<gridC, 256, 0, stream>>>(skipB, BpD1, BpD2, bd1, bd2,
                                          (float*)d_out, nT8C);
}